// Round 1
// baseline (1181.352 us; speedup 1.0000x reference)
//
#include <hip/hip_runtime.h>
#include <math.h>

#define NN 50000
#define EE 800000
#define GG 512

__device__ __forceinline__ float wave16_sum(float p) {
    p += __shfl_xor(p, 1);
    p += __shfl_xor(p, 2);
    p += __shfl_xor(p, 4);
    p += __shfl_xor(p, 8);
    return p;
}

// ---------------- CSR build ----------------
__global__ void deg_kernel(const int* __restrict__ ei, int* __restrict__ deg) {
    int e = blockIdx.x * 256 + threadIdx.x;
    if (e < EE) atomicAdd(&deg[ei[EE + e]], 1);
}

__global__ void scan1(const int* __restrict__ deg, int* __restrict__ incl, int* __restrict__ bsum) {
    __shared__ int sh[256];
    int t = threadIdx.x;
    int n = blockIdx.x * 256 + t;
    int vv = (n < NN) ? deg[n] : 0;
    sh[t] = vv; __syncthreads();
    for (int off = 1; off < 256; off <<= 1) {
        int u = (t >= off) ? sh[t - off] : 0;
        __syncthreads();
        sh[t] += u;
        __syncthreads();
    }
    if (n < NN) incl[n] = sh[t];
    if (t == 255) bsum[blockIdx.x] = sh[255];
}

__global__ void scan2(int* __restrict__ bsum, int nblk) {
    __shared__ int sh[256];
    int t = threadIdx.x;
    int vv = (t < nblk) ? bsum[t] : 0;
    sh[t] = vv; __syncthreads();
    for (int off = 1; off < 256; off <<= 1) {
        int u = (t >= off) ? sh[t - off] : 0;
        __syncthreads();
        sh[t] += u;
        __syncthreads();
    }
    bsum[t] = sh[t];
}

__global__ void scan3(int* __restrict__ rowst, const int* __restrict__ deg,
                      const int* __restrict__ bsum, int* __restrict__ cursor) {
    int n = blockIdx.x * 256 + threadIdx.x;
    if (n >= NN) return;
    int off = (blockIdx.x > 0) ? bsum[blockIdx.x - 1] : 0;
    int excl = rowst[n] - deg[n] + off;
    rowst[n] = excl;
    cursor[n] = excl;
}

__global__ void fill_kernel(const int* __restrict__ ei, int* __restrict__ cursor,
                            int* __restrict__ esrc) {
    int e = blockIdx.x * 256 + threadIdx.x;
    if (e < EE) {
        int s = ei[e], d = ei[EE + e];
        int pos = atomicAdd(&cursor[d], 1);
        esrc[pos] = s;
    }
}

// ---------------- GEMM: C[N,ncol] = X[N,64] @ W[64,ncol] + b ----------------
__global__ __launch_bounds__(256) void gemm_xw(const float* __restrict__ X,
                                               const float* __restrict__ W,
                                               const float* __restrict__ Bv,
                                               float* __restrict__ C, int ncol) {
    __shared__ float xs[64][64];
    int t = threadIdx.x;
    int row0 = blockIdx.x * 64;
    for (int i = t; i < 64 * 16; i += 256) {
        int r = i >> 4, c4 = i & 15;
        int gr = row0 + r;
        float4 val = make_float4(0.f, 0.f, 0.f, 0.f);
        if (gr < NN) val = *(const float4*)(X + gr * 64 + c4 * 4);
        *(float4*)&xs[r][c4 * 4] = val;
    }
    __syncthreads();
    if (ncol == 128) {
        int cg = t & 31, nl = t >> 5;
        float4 bb = *(const float4*)(Bv + cg * 4);
        for (int rep = 0; rep < 8; ++rep) {
            int n = nl + rep * 8;
            float ax = bb.x, ay = bb.y, az = bb.z, aw = bb.w;
            #pragma unroll
            for (int c = 0; c < 64; ++c) {
                float xv = xs[n][c];
                float4 w = *(const float4*)(W + c * 128 + cg * 4);
                ax += xv * w.x; ay += xv * w.y; az += xv * w.z; aw += xv * w.w;
            }
            int gn = row0 + n;
            if (gn < NN) {
                float4 o; o.x = ax; o.y = ay; o.z = az; o.w = aw;
                *(float4*)(C + gn * 128 + cg * 4) = o;
            }
        }
    } else {
        int cg = t & 15, nl = t >> 4;
        float4 bb = *(const float4*)(Bv + cg * 4);
        for (int rep = 0; rep < 4; ++rep) {
            int n = nl + rep * 16;
            float ax = bb.x, ay = bb.y, az = bb.z, aw = bb.w;
            #pragma unroll
            for (int c = 0; c < 64; ++c) {
                float xv = xs[n][c];
                float4 w = *(const float4*)(W + c * 64 + cg * 4);
                ax += xv * w.x; ay += xv * w.y; az += xv * w.z; aw += xv * w.w;
            }
            int gn = row0 + n;
            if (gn < NN) {
                float4 o; o.x = ax; o.y = ay; o.z = az; o.w = aw;
                *(float4*)(C + gn * 64 + cg * 4) = o;
            }
        }
    }
}

// ---------------- per-node attention aggregation (online softmax) ----------------
__global__ __launch_bounds__(256) void agg_kernel(
    const float* __restrict__ q, const float* __restrict__ k,
    const float* __restrict__ v, const float* __restrict__ skip,
    const int* __restrict__ rowst, const int* __restrict__ deg,
    const int* __restrict__ esrc, const float* __restrict__ gamma,
    const float* __restrict__ beta, float* __restrict__ hout, int do_ln) {
    int wave = threadIdx.x >> 6;
    int lane = threadIdx.x & 63;
    int node = blockIdx.x * 4 + wave;
    if (node >= NN) return;
    int j = lane & 15;
    int slot = lane >> 4;

    float4 q0 = *(const float4*)(q + node * 128 + j * 4);
    float4 q1 = *(const float4*)(q + node * 128 + 64 + j * 4);
    float m0 = -INFINITY, m1 = -INFINITY;
    float l0 = 0.f, l1 = 0.f;
    float acc0[4] = {0.f, 0.f, 0.f, 0.f};
    float acc1[4] = {0.f, 0.f, 0.f, 0.f};

    int st = rowst[node];
    int dg = deg[node];
    for (int i = slot; i < dg; i += 4) {
        int s = esrc[st + i];
        const float* kb = k + s * 128 + j * 4;
        float4 k0 = *(const float4*)kb;
        float4 k1 = *(const float4*)(kb + 64);
        float p0 = q0.x * k0.x + q0.y * k0.y + q0.z * k0.z + q0.w * k0.w;
        float p1 = q1.x * k1.x + q1.y * k1.y + q1.z * k1.z + q1.w * k1.w;
        p0 = wave16_sum(p0) * 0.125f;
        p1 = wave16_sum(p1) * 0.125f;
        const float* vb = v + s * 128 + j * 4;
        float4 v0 = *(const float4*)vb;
        float4 v1 = *(const float4*)(vb + 64);
        float va0[4] = {v0.x, v0.y, v0.z, v0.w};
        float va1[4] = {v1.x, v1.y, v1.z, v1.w};
        {
            float nm = fmaxf(m0, p0);
            float e = __expf(p0 - nm);
            float f = (m0 > -INFINITY) ? __expf(m0 - nm) : 0.f;
            l0 = l0 * f + e;
            #pragma unroll
            for (int r = 0; r < 4; ++r) acc0[r] = acc0[r] * f + e * va0[r];
            m0 = nm;
        }
        {
            float nm = fmaxf(m1, p1);
            float e = __expf(p1 - nm);
            float f = (m1 > -INFINITY) ? __expf(m1 - nm) : 0.f;
            l1 = l1 * f + e;
            #pragma unroll
            for (int r = 0; r < 4; ++r) acc1[r] = acc1[r] * f + e * va1[r];
            m1 = nm;
        }
    }
    // butterfly-merge the 4 slot states (masks 16, 32)
    #pragma unroll
    for (int mask = 16; mask <= 32; mask <<= 1) {
        {
            float mo = __shfl_xor(m0, mask);
            float lo = __shfl_xor(l0, mask);
            float ao[4];
            #pragma unroll
            for (int r = 0; r < 4; ++r) ao[r] = __shfl_xor(acc0[r], mask);
            float nm = fmaxf(m0, mo);
            float fa = (m0 > -INFINITY) ? __expf(m0 - nm) : 0.f;
            float fb = (mo > -INFINITY) ? __expf(mo - nm) : 0.f;
            l0 = l0 * fa + lo * fb;
            #pragma unroll
            for (int r = 0; r < 4; ++r) acc0[r] = acc0[r] * fa + ao[r] * fb;
            m0 = nm;
        }
        {
            float mo = __shfl_xor(m1, mask);
            float lo = __shfl_xor(l1, mask);
            float ao[4];
            #pragma unroll
            for (int r = 0; r < 4; ++r) ao[r] = __shfl_xor(acc1[r], mask);
            float nm = fmaxf(m1, mo);
            float fa = (m1 > -INFINITY) ? __expf(m1 - nm) : 0.f;
            float fb = (mo > -INFINITY) ? __expf(mo - nm) : 0.f;
            l1 = l1 * fa + lo * fb;
            #pragma unroll
            for (int r = 0; r < 4; ++r) acc1[r] = acc1[r] * fa + ao[r] * fb;
            m1 = nm;
        }
    }
    float i0 = 1.f / (l0 + 1e-16f);
    float i1 = 1.f / (l1 + 1e-16f);
    float4 sk = *(const float4*)(skip + node * 64 + j * 4);
    float ska[4] = {sk.x, sk.y, sk.z, sk.w};
    float val[4];
    #pragma unroll
    for (int r = 0; r < 4; ++r) {
        float o = 0.5f * (acc0[r] * i0 + acc1[r] * i1) + ska[r];
        val[r] = fmaxf(o, 0.f);
    }
    if (do_ln) {
        float s = val[0] + val[1] + val[2] + val[3];
        s = wave16_sum(s);
        float mu = s * (1.f / 64.f);
        float ss = 0.f;
        #pragma unroll
        for (int r = 0; r < 4; ++r) { float d = val[r] - mu; ss += d * d; }
        ss = wave16_sum(ss);
        float rstd = rsqrtf(ss * (1.f / 64.f) + 1e-5f);
        float4 g4 = *(const float4*)(gamma + j * 4);
        float4 b4 = *(const float4*)(beta + j * 4);
        float ga[4] = {g4.x, g4.y, g4.z, g4.w};
        float ba[4] = {b4.x, b4.y, b4.z, b4.w};
        #pragma unroll
        for (int r = 0; r < 4; ++r) val[r] = (val[r] - mu) * rstd * ga[r] + ba[r];
    }
    if (slot == 0) {
        float4 o; o.x = val[0]; o.y = val[1]; o.z = val[2]; o.w = val[3];
        *(float4*)(hout + node * 64 + j * 4) = o;
    }
}

// ---------------- pooling ----------------
__global__ void pool_kernel(const float* __restrict__ h, const int* __restrict__ batch,
                            float* __restrict__ gsum, float* __restrict__ gcnt) {
    int gid = blockIdx.x * 256 + threadIdx.x;
    if (gid >= NN * 64) return;
    int n = gid >> 6, c = gid & 63;
    int g = batch[n];
    atomicAdd(&gsum[g * 64 + c], h[gid]);
    if (c == 0) atomicAdd(&gcnt[g], 1.f);
}

__global__ void final_kernel(const float* __restrict__ gsum, const float* __restrict__ gcnt,
                             const float* __restrict__ Wout, const float* __restrict__ bout,
                             float* __restrict__ out) {
    int g = blockIdx.x, c = threadIdx.x;
    float cnt = fmaxf(gcnt[g], 1.f);
    float val = gsum[g * 64 + c] / cnt * Wout[c];
    #pragma unroll
    for (int mk = 1; mk < 64; mk <<= 1) val += __shfl_xor(val, mk);
    if (c == 0) out[g] = val + bout[0];
}

extern "C" void kernel_launch(void* const* d_in, const int* in_sizes, int n_in,
                              void* d_out, int out_size, void* d_ws, size_t ws_size,
                              hipStream_t stream) {
    const float* x    = (const float*)d_in[0];
    const int*   ei   = (const int*)d_in[1];
    const int*   batch= (const int*)d_in[2];
    const float* Wq   = (const float*)d_in[4];
    const float* bq   = (const float*)d_in[5];
    const float* Wk   = (const float*)d_in[6];
    const float* bk   = (const float*)d_in[7];
    const float* Wv   = (const float*)d_in[8];
    const float* bv   = (const float*)d_in[9];
    const float* Ws   = (const float*)d_in[10];
    const float* bs   = (const float*)d_in[11];
    const float* lng  = (const float*)d_in[12];
    const float* lnb  = (const float*)d_in[13];
    const float* Wout = (const float*)d_in[14];
    const float* bout = (const float*)d_in[15];
    float* out = (float*)d_out;

    float* q    = (float*)d_ws;
    float* k    = q + (size_t)NN * 128;
    float* v    = k + (size_t)NN * 128;
    float* skip = v + (size_t)NN * 128;
    float* h0   = skip + (size_t)NN * 64;
    float* h1   = h0 + (size_t)NN * 64;
    float* gsum = h1 + (size_t)NN * 64;
    float* gcnt = gsum + (size_t)GG * 64;
    int* deg    = (int*)(gcnt + GG);
    int* rowst  = deg + NN;
    int* cursor = rowst + NN;
    int* bsum   = cursor + NN;
    int* esrc   = bsum + 256;

    hipMemsetAsync(deg, 0, NN * sizeof(int), stream);
    hipMemsetAsync(gsum, 0, (GG * 64 + GG) * sizeof(float), stream);

    const int NB = (NN + 255) / 256;  // 196
    deg_kernel<<<(EE + 255) / 256, 256, 0, stream>>>(ei, deg);
    scan1<<<NB, 256, 0, stream>>>(deg, rowst, bsum);
    scan2<<<1, 256, 0, stream>>>(bsum, NB);
    scan3<<<NB, 256, 0, stream>>>(rowst, deg, bsum, cursor);
    fill_kernel<<<(EE + 255) / 256, 256, 0, stream>>>(ei, cursor, esrc);

    const int GEMM_GRID = (NN + 63) / 64;  // 782
    const float* hin = x;
    float* houts[3] = {h0, h1, h0};
    for (int l = 0; l < 3; ++l) {
        gemm_xw<<<GEMM_GRID, 256, 0, stream>>>(hin, Wq + (size_t)l * 64 * 128, bq + (size_t)l * 128, q, 128);
        gemm_xw<<<GEMM_GRID, 256, 0, stream>>>(hin, Wk + (size_t)l * 64 * 128, bk + (size_t)l * 128, k, 128);
        gemm_xw<<<GEMM_GRID, 256, 0, stream>>>(hin, Wv + (size_t)l * 64 * 128, bv + (size_t)l * 128, v, 128);
        gemm_xw<<<GEMM_GRID, 256, 0, stream>>>(hin, Ws + (size_t)l * 64 * 64, bs + (size_t)l * 64, skip, 64);
        int do_ln = (l < 2) ? 1 : 0;
        agg_kernel<<<(NN + 3) / 4, 256, 0, stream>>>(q, k, v, skip, rowst, deg, esrc,
                                                     do_ln ? lng + (size_t)l * 64 : lng,
                                                     do_ln ? lnb + (size_t)l * 64 : lnb,
                                                     houts[l], do_ln);
        hin = houts[l];
    }
    pool_kernel<<<(NN * 64 + 255) / 256, 256, 0, stream>>>(hin, batch, gsum, gcnt);
    final_kernel<<<GG, 64, 0, stream>>>(gsum, gcnt, Wout, bout, out);
}

// Round 3
// 668.776 us; speedup vs baseline: 1.7664x; 1.7664x over previous
//
#include <hip/hip_runtime.h>
#include <math.h>

#define NN 50000
#define EE 800000
#define GG 512

__device__ __forceinline__ float wave16_sum(float p) {
    p += __shfl_xor(p, 1);
    p += __shfl_xor(p, 2);
    p += __shfl_xor(p, 4);
    p += __shfl_xor(p, 8);
    return p;
}

// ---------------- CSR build ----------------
__global__ void deg_kernel(const int* __restrict__ ei, int* __restrict__ deg) {
    int e = blockIdx.x * 256 + threadIdx.x;
    if (e < EE) atomicAdd(&deg[ei[EE + e]], 1);
}

__global__ void scan1(const int* __restrict__ deg, int* __restrict__ incl, int* __restrict__ bsum) {
    __shared__ int sh[256];
    int t = threadIdx.x;
    int n = blockIdx.x * 256 + t;
    int vv = (n < NN) ? deg[n] : 0;
    sh[t] = vv; __syncthreads();
    for (int off = 1; off < 256; off <<= 1) {
        int u = (t >= off) ? sh[t - off] : 0;
        __syncthreads();
        sh[t] += u;
        __syncthreads();
    }
    if (n < NN) incl[n] = sh[t];
    if (t == 255) bsum[blockIdx.x] = sh[255];
}

__global__ void scan2(int* __restrict__ bsum, int nblk) {
    __shared__ int sh[256];
    int t = threadIdx.x;
    int vv = (t < nblk) ? bsum[t] : 0;
    sh[t] = vv; __syncthreads();
    for (int off = 1; off < 256; off <<= 1) {
        int u = (t >= off) ? sh[t - off] : 0;
        __syncthreads();
        sh[t] += u;
        __syncthreads();
    }
    bsum[t] = sh[t];
}

__global__ void scan3(int* __restrict__ rowst, const int* __restrict__ deg,
                      const int* __restrict__ bsum, int* __restrict__ cursor) {
    int n = blockIdx.x * 256 + threadIdx.x;
    if (n >= NN) return;
    int off = (blockIdx.x > 0) ? bsum[blockIdx.x - 1] : 0;
    int excl = rowst[n] - deg[n] + off;
    rowst[n] = excl;
    cursor[n] = excl;
}

__global__ void fill_kernel(const int* __restrict__ ei, int* __restrict__ cursor,
                            int* __restrict__ esrc) {
    int e = blockIdx.x * 256 + threadIdx.x;
    if (e < EE) {
        int s = ei[e], d = ei[EE + e];
        int pos = atomicAdd(&cursor[d], 1);
        esrc[pos] = s;
    }
}

// ---------------- fused per-layer GEMM: q,k,v (64->128) + skip (64->64) ----------------
__device__ __forceinline__ void compute128(const float (*xs)[68], const float (*ws)[132],
                                           const float* __restrict__ bias,
                                           float* __restrict__ out, int row0, int t) {
    int rg = t >> 4, cg = t & 15;
    int r0 = rg * 4;
    float4 b0 = *(const float4*)(bias + cg * 8);
    float4 b1 = *(const float4*)(bias + cg * 8 + 4);
    float acc[4][8];
    #pragma unroll
    for (int rr = 0; rr < 4; ++rr) {
        acc[rr][0] = b0.x; acc[rr][1] = b0.y; acc[rr][2] = b0.z; acc[rr][3] = b0.w;
        acc[rr][4] = b1.x; acc[rr][5] = b1.y; acc[rr][6] = b1.z; acc[rr][7] = b1.w;
    }
    #pragma unroll 8
    for (int c = 0; c < 64; ++c) {
        float xr[4];
        #pragma unroll
        for (int rr = 0; rr < 4; ++rr) xr[rr] = xs[r0 + rr][c];
        float4 wA = *(const float4*)&ws[c][cg * 8];
        float4 wB = *(const float4*)&ws[c][cg * 8 + 4];
        float wv8[8] = {wA.x, wA.y, wA.z, wA.w, wB.x, wB.y, wB.z, wB.w};
        #pragma unroll
        for (int rr = 0; rr < 4; ++rr)
            #pragma unroll
            for (int cc = 0; cc < 8; ++cc)
                acc[rr][cc] += xr[rr] * wv8[cc];
    }
    #pragma unroll
    for (int rr = 0; rr < 4; ++rr) {
        int gr = row0 + r0 + rr;
        if (gr < NN) {
            float4 o0 = {acc[rr][0], acc[rr][1], acc[rr][2], acc[rr][3]};
            float4 o1 = {acc[rr][4], acc[rr][5], acc[rr][6], acc[rr][7]};
            *(float4*)(out + (size_t)gr * 128 + cg * 8) = o0;
            *(float4*)(out + (size_t)gr * 128 + cg * 8 + 4) = o1;
        }
    }
}

__device__ __forceinline__ void compute64(const float (*xs)[68], const float (*ws)[132],
                                          const float* __restrict__ bias,
                                          float* __restrict__ out, int row0, int t) {
    int rg = t >> 4, cg = t & 15;
    int r0 = rg * 4;
    float4 b0 = *(const float4*)(bias + cg * 4);
    float acc[4][4];
    #pragma unroll
    for (int rr = 0; rr < 4; ++rr) {
        acc[rr][0] = b0.x; acc[rr][1] = b0.y; acc[rr][2] = b0.z; acc[rr][3] = b0.w;
    }
    #pragma unroll 8
    for (int c = 0; c < 64; ++c) {
        float xr[4];
        #pragma unroll
        for (int rr = 0; rr < 4; ++rr) xr[rr] = xs[r0 + rr][c];
        float4 w = *(const float4*)&ws[c][cg * 4];
        float wv4[4] = {w.x, w.y, w.z, w.w};
        #pragma unroll
        for (int rr = 0; rr < 4; ++rr)
            #pragma unroll
            for (int cc = 0; cc < 4; ++cc)
                acc[rr][cc] += xr[rr] * wv4[cc];
    }
    #pragma unroll
    for (int rr = 0; rr < 4; ++rr) {
        int gr = row0 + r0 + rr;
        if (gr < NN) {
            float4 o0 = {acc[rr][0], acc[rr][1], acc[rr][2], acc[rr][3]};
            *(float4*)(out + (size_t)gr * 64 + cg * 4) = o0;
        }
    }
}

__global__ __launch_bounds__(256) void gemm_fused(const float* __restrict__ X,
    const float* __restrict__ Wq, const float* __restrict__ bq,
    const float* __restrict__ Wk, const float* __restrict__ bk,
    const float* __restrict__ Wv, const float* __restrict__ bv,
    const float* __restrict__ Wsk, const float* __restrict__ bsk,
    float* __restrict__ q, float* __restrict__ k, float* __restrict__ v,
    float* __restrict__ skip) {
    __shared__ float xs[64][68];
    __shared__ float ws[64][132];
    int t = threadIdx.x;
    int row0 = blockIdx.x * 64;
    for (int i = t; i < 64 * 16; i += 256) {
        int r = i >> 4, c4 = i & 15;
        int gr = row0 + r;
        float4 val = make_float4(0.f, 0.f, 0.f, 0.f);
        if (gr < NN) val = *(const float4*)(X + (size_t)gr * 64 + c4 * 4);
        *(float4*)&xs[r][c4 * 4] = val;
    }
    const float* Wm[3] = {Wq, Wk, Wv};
    const float* bm[3] = {bq, bk, bv};
    float* om[3] = {q, k, v};
    #pragma unroll 1
    for (int m = 0; m < 3; ++m) {
        __syncthreads();
        for (int i = t; i < 64 * 32; i += 256) {
            int r = i >> 5, c4 = i & 31;
            *(float4*)&ws[r][c4 * 4] = *(const float4*)(Wm[m] + r * 128 + c4 * 4);
        }
        __syncthreads();
        compute128(xs, ws, bm[m], om[m], row0, t);
    }
    __syncthreads();
    for (int i = t; i < 64 * 16; i += 256) {
        int r = i >> 4, c4 = i & 15;
        *(float4*)&ws[r][c4 * 4] = *(const float4*)(Wsk + r * 64 + c4 * 4);
    }
    __syncthreads();
    compute64(xs, ws, bsk, skip, row0, t);
}

// ---------------- per-node attention aggregation (online softmax, 2-edge unroll) ----------------
__global__ __launch_bounds__(256) void agg_kernel(
    const float* __restrict__ q, const float* __restrict__ k,
    const float* __restrict__ v, const float* __restrict__ skip,
    const int* __restrict__ rowst, const int* __restrict__ deg,
    const int* __restrict__ esrc, const float* __restrict__ gamma,
    const float* __restrict__ beta, float* __restrict__ hout, int do_ln) {
    int wave = threadIdx.x >> 6;
    int lane = threadIdx.x & 63;
    int node = blockIdx.x * 4 + wave;
    if (node >= NN) return;
    int j = lane & 15;
    int slot = lane >> 4;

    float4 q0 = *(const float4*)(q + (size_t)node * 128 + j * 4);
    float4 q1 = *(const float4*)(q + (size_t)node * 128 + 64 + j * 4);
    float m0 = -INFINITY, m1 = -INFINITY;
    float l0 = 0.f, l1 = 0.f;
    float acc0[4] = {0.f, 0.f, 0.f, 0.f};
    float acc1[4] = {0.f, 0.f, 0.f, 0.f};

    int st = rowst[node];
    int dg = deg[node];
    for (int i = slot; i < dg; i += 8) {
        int i2 = i + 4;
        bool has2 = i2 < dg;
        int s0 = esrc[st + i];
        int s1 = has2 ? esrc[st + i2] : s0;
        const float* kb0 = k + (size_t)s0 * 128 + j * 4;
        const float* kb1 = k + (size_t)s1 * 128 + j * 4;
        float4 k00 = *(const float4*)kb0;
        float4 k01 = *(const float4*)(kb0 + 64);
        float4 k10 = *(const float4*)kb1;
        float4 k11 = *(const float4*)(kb1 + 64);
        const float* vb0 = v + (size_t)s0 * 128 + j * 4;
        const float* vb1 = v + (size_t)s1 * 128 + j * 4;
        float4 v00 = *(const float4*)vb0;
        float4 v01 = *(const float4*)(vb0 + 64);
        float4 v10 = *(const float4*)vb1;
        float4 v11 = *(const float4*)(vb1 + 64);
        float p00 = q0.x * k00.x + q0.y * k00.y + q0.z * k00.z + q0.w * k00.w;
        float p01 = q1.x * k01.x + q1.y * k01.y + q1.z * k01.z + q1.w * k01.w;
        float p10 = q0.x * k10.x + q0.y * k10.y + q0.z * k10.z + q0.w * k10.w;
        float p11 = q1.x * k11.x + q1.y * k11.y + q1.z * k11.z + q1.w * k11.w;
        p00 = wave16_sum(p00) * 0.125f;
        p01 = wave16_sum(p01) * 0.125f;
        p10 = wave16_sum(p10) * 0.125f;
        p11 = wave16_sum(p11) * 0.125f;
        {
            float nm = fmaxf(m0, p00);
            float e = __expf(p00 - nm);
            float f = (m0 > -INFINITY) ? __expf(m0 - nm) : 0.f;
            l0 = l0 * f + e;
            acc0[0] = acc0[0] * f + e * v00.x;
            acc0[1] = acc0[1] * f + e * v00.y;
            acc0[2] = acc0[2] * f + e * v00.z;
            acc0[3] = acc0[3] * f + e * v00.w;
            m0 = nm;
        }
        {
            float nm = fmaxf(m1, p01);
            float e = __expf(p01 - nm);
            float f = (m1 > -INFINITY) ? __expf(m1 - nm) : 0.f;
            l1 = l1 * f + e;
            acc1[0] = acc1[0] * f + e * v01.x;
            acc1[1] = acc1[1] * f + e * v01.y;
            acc1[2] = acc1[2] * f + e * v01.z;
            acc1[3] = acc1[3] * f + e * v01.w;
            m1 = nm;
        }
        if (has2) {
            {
                float nm = fmaxf(m0, p10);
                float e = __expf(p10 - nm);
                float f = (m0 > -INFINITY) ? __expf(m0 - nm) : 0.f;
                l0 = l0 * f + e;
                acc0[0] = acc0[0] * f + e * v10.x;
                acc0[1] = acc0[1] * f + e * v10.y;
                acc0[2] = acc0[2] * f + e * v10.z;
                acc0[3] = acc0[3] * f + e * v10.w;
                m0 = nm;
            }
            {
                float nm = fmaxf(m1, p11);
                float e = __expf(p11 - nm);
                float f = (m1 > -INFINITY) ? __expf(m1 - nm) : 0.f;
                l1 = l1 * f + e;
                acc1[0] = acc1[0] * f + e * v11.x;
                acc1[1] = acc1[1] * f + e * v11.y;
                acc1[2] = acc1[2] * f + e * v11.z;
                acc1[3] = acc1[3] * f + e * v11.w;
                m1 = nm;
            }
        }
    }
    // butterfly-merge the 4 slot states (masks 16, 32)
    #pragma unroll
    for (int mask = 16; mask <= 32; mask <<= 1) {
        {
            float mo = __shfl_xor(m0, mask);
            float lo = __shfl_xor(l0, mask);
            float ao[4];
            #pragma unroll
            for (int r = 0; r < 4; ++r) ao[r] = __shfl_xor(acc0[r], mask);
            float nm = fmaxf(m0, mo);
            float fa = (m0 > -INFINITY) ? __expf(m0 - nm) : 0.f;
            float fb = (mo > -INFINITY) ? __expf(mo - nm) : 0.f;
            l0 = l0 * fa + lo * fb;
            #pragma unroll
            for (int r = 0; r < 4; ++r) acc0[r] = acc0[r] * fa + ao[r] * fb;
            m0 = nm;
        }
        {
            float mo = __shfl_xor(m1, mask);
            float lo = __shfl_xor(l1, mask);
            float ao[4];
            #pragma unroll
            for (int r = 0; r < 4; ++r) ao[r] = __shfl_xor(acc1[r], mask);
            float nm = fmaxf(m1, mo);
            float fa = (m1 > -INFINITY) ? __expf(m1 - nm) : 0.f;
            float fb = (mo > -INFINITY) ? __expf(mo - nm) : 0.f;
            l1 = l1 * fa + lo * fb;
            #pragma unroll
            for (int r = 0; r < 4; ++r) acc1[r] = acc1[r] * fa + ao[r] * fb;
            m1 = nm;
        }
    }
    float i0 = 1.f / (l0 + 1e-16f);
    float i1 = 1.f / (l1 + 1e-16f);
    float4 sk = *(const float4*)(skip + (size_t)node * 64 + j * 4);
    float ska[4] = {sk.x, sk.y, sk.z, sk.w};
    float val[4];
    #pragma unroll
    for (int r = 0; r < 4; ++r) {
        float o = 0.5f * (acc0[r] * i0 + acc1[r] * i1) + ska[r];
        val[r] = fmaxf(o, 0.f);
    }
    if (do_ln) {
        float s = val[0] + val[1] + val[2] + val[3];
        s = wave16_sum(s);
        float mu = s * (1.f / 64.f);
        float ss = 0.f;
        #pragma unroll
        for (int r = 0; r < 4; ++r) { float d = val[r] - mu; ss += d * d; }
        ss = wave16_sum(ss);
        float rstd = rsqrtf(ss * (1.f / 64.f) + 1e-5f);
        float4 g4 = *(const float4*)(gamma + j * 4);
        float4 b4 = *(const float4*)(beta + j * 4);
        float ga[4] = {g4.x, g4.y, g4.z, g4.w};
        float ba[4] = {b4.x, b4.y, b4.z, b4.w};
        #pragma unroll
        for (int r = 0; r < 4; ++r) val[r] = (val[r] - mu) * rstd * ga[r] + ba[r];
    }
    if (slot == 0) {
        float4 o; o.x = val[0]; o.y = val[1]; o.z = val[2]; o.w = val[3];
        *(float4*)(hout + (size_t)node * 64 + j * 4) = o;
    }
}

// ---------------- fused pool + final projection (batch is sorted) ----------------
__device__ __forceinline__ int lbound(const int* __restrict__ a, int n, int key) {
    int lo = 0, hi = n;
    while (lo < hi) {
        int mid = (lo + hi) >> 1;
        if (a[mid] < key) lo = mid + 1; else hi = mid;
    }
    return lo;
}

__global__ __launch_bounds__(256) void pool_final_kernel(
    const float* __restrict__ h, const int* __restrict__ batch,
    const float* __restrict__ Wout, const float* __restrict__ bout,
    float* __restrict__ out) {
    __shared__ int sh_lo, sh_hi;
    __shared__ float part[4][64];
    int g = blockIdx.x;
    int t = threadIdx.x;
    if (t == 0) {
        sh_lo = lbound(batch, NN, g);
        sh_hi = lbound(batch, NN, g + 1);
    }
    __syncthreads();
    int lo = sh_lo, hi = sh_hi;
    int c = t & 63, w = t >> 6;
    float s = 0.f;
    for (int n = lo + w; n < hi; n += 4) s += h[(size_t)n * 64 + c];
    part[w][c] = s;
    __syncthreads();
    if (t < 64) {
        float tot = part[0][t] + part[1][t] + part[2][t] + part[3][t];
        float cnt = (float)(hi - lo);
        float val = tot / fmaxf(cnt, 1.f) * Wout[t];
        #pragma unroll
        for (int mk = 1; mk < 64; mk <<= 1) val += __shfl_xor(val, mk);
        if (t == 0) out[g] = val + bout[0];
    }
}

extern "C" void kernel_launch(void* const* d_in, const int* in_sizes, int n_in,
                              void* d_out, int out_size, void* d_ws, size_t ws_size,
                              hipStream_t stream) {
    const float* x    = (const float*)d_in[0];
    const int*   ei   = (const int*)d_in[1];
    const int*   batch= (const int*)d_in[2];
    const float* Wq   = (const float*)d_in[4];
    const float* bq   = (const float*)d_in[5];
    const float* Wk   = (const float*)d_in[6];
    const float* bk   = (const float*)d_in[7];
    const float* Wv   = (const float*)d_in[8];
    const float* bv   = (const float*)d_in[9];
    const float* Ws   = (const float*)d_in[10];
    const float* bs   = (const float*)d_in[11];
    const float* lng  = (const float*)d_in[12];
    const float* lnb  = (const float*)d_in[13];
    const float* Wout = (const float*)d_in[14];
    const float* bout = (const float*)d_in[15];
    float* out = (float*)d_out;

    float* q    = (float*)d_ws;
    float* k    = q + (size_t)NN * 128;
    float* v    = k + (size_t)NN * 128;
    float* skip = v + (size_t)NN * 128;
    float* h0   = skip + (size_t)NN * 64;
    float* h1   = h0 + (size_t)NN * 64;
    int* deg    = (int*)(h1 + (size_t)NN * 64);
    int* rowst  = deg + NN;
    int* cursor = rowst + NN;
    int* bsum   = cursor + NN;
    int* esrc   = bsum + 256;

    hipMemsetAsync(deg, 0, NN * sizeof(int), stream);

    const int NB = (NN + 255) / 256;  // 196
    deg_kernel<<<(EE + 255) / 256, 256, 0, stream>>>(ei, deg);
    scan1<<<NB, 256, 0, stream>>>(deg, rowst, bsum);
    scan2<<<1, 256, 0, stream>>>(bsum, NB);
    scan3<<<NB, 256, 0, stream>>>(rowst, deg, bsum, cursor);
    fill_kernel<<<(EE + 255) / 256, 256, 0, stream>>>(ei, cursor, esrc);

    const int GEMM_GRID = (NN + 63) / 64;  // 782
    const float* hin = x;
    float* houts[3] = {h0, h1, h0};
    for (int l = 0; l < 3; ++l) {
        gemm_fused<<<GEMM_GRID, 256, 0, stream>>>(hin,
            Wq + (size_t)l * 64 * 128, bq + (size_t)l * 128,
            Wk + (size_t)l * 64 * 128, bk + (size_t)l * 128,
            Wv + (size_t)l * 64 * 128, bv + (size_t)l * 128,
            Ws + (size_t)l * 64 * 64, bs + (size_t)l * 64,
            q, k, v, skip);
        int do_ln = (l < 2) ? 1 : 0;
        agg_kernel<<<(NN + 3) / 4, 256, 0, stream>>>(q, k, v, skip, rowst, deg, esrc,
                                                     lng + (size_t)(do_ln ? l : 0) * 64,
                                                     lnb + (size_t)(do_ln ? l : 0) * 64,
                                                     houts[l], do_ln);
        hin = houts[l];
    }
    pool_final_kernel<<<GG, 256, 0, stream>>>(hin, batch, Wout, bout, out);
}

// Round 6
// 663.531 us; speedup vs baseline: 1.7804x; 1.0079x over previous
//
#include <hip/hip_runtime.h>
#include <math.h>

#define NN 50000
#define EE 800000
#define GG 512

__device__ __forceinline__ float wave16_sum(float p) {
    p += __shfl_xor(p, 1);
    p += __shfl_xor(p, 2);
    p += __shfl_xor(p, 4);
    p += __shfl_xor(p, 8);
    return p;
}
__device__ __forceinline__ float dot4(float4 a, float4 b) {
    return a.x * b.x + a.y * b.y + a.z * b.z + a.w * b.w;
}

// ---------------- CSR build ----------------
__global__ void deg_kernel(const int* __restrict__ ei, int* __restrict__ deg) {
    int e = blockIdx.x * 256 + threadIdx.x;
    if (e < EE) atomicAdd(&deg[ei[EE + e]], 1);
}

__global__ void scan1(const int* __restrict__ deg, int* __restrict__ incl, int* __restrict__ bsum) {
    __shared__ int sh[256];
    int t = threadIdx.x;
    int n = blockIdx.x * 256 + t;
    int vv = (n < NN) ? deg[n] : 0;
    sh[t] = vv; __syncthreads();
    for (int off = 1; off < 256; off <<= 1) {
        int u = (t >= off) ? sh[t - off] : 0;
        __syncthreads();
        sh[t] += u;
        __syncthreads();
    }
    if (n < NN) incl[n] = sh[t];
    if (t == 255) bsum[blockIdx.x] = sh[255];
}

__global__ void scan2(int* __restrict__ bsum, int nblk) {
    __shared__ int sh[256];
    int t = threadIdx.x;
    int vv = (t < nblk) ? bsum[t] : 0;
    sh[t] = vv; __syncthreads();
    for (int off = 1; off < 256; off <<= 1) {
        int u = (t >= off) ? sh[t - off] : 0;
        __syncthreads();
        sh[t] += u;
        __syncthreads();
    }
    bsum[t] = sh[t];
}

__global__ void scan3(int* __restrict__ rowst, const int* __restrict__ deg,
                      const int* __restrict__ bsum, int* __restrict__ cursor) {
    int n = blockIdx.x * 256 + threadIdx.x;
    if (n >= NN) return;
    int off = (blockIdx.x > 0) ? bsum[blockIdx.x - 1] : 0;
    int excl = rowst[n] - deg[n] + off;
    rowst[n] = excl;
    cursor[n] = excl;
}

__global__ void fill_kernel(const int* __restrict__ ei, int* __restrict__ cursor,
                            int* __restrict__ esrc) {
    int e = blockIdx.x * 256 + threadIdx.x;
    if (e < EE) {
        int s = ei[e], d = ei[EE + e];
        int pos = atomicAdd(&cursor[d], 1);
        esrc[pos] = s;
    }
}

// ---------------- fused per-layer GEMM: q,k,v (64->128) + skip (64->64) ----------------
__device__ __forceinline__ void compute128(const float (*xs)[68], const float (*ws)[132],
                                           const float* __restrict__ bias,
                                           float* __restrict__ out, int row_stride,
                                           int row0, int t) {
    int rg = t >> 4, cg = t & 15;
    int r0 = rg * 4;
    float4 b0 = *(const float4*)(bias + cg * 8);
    float4 b1 = *(const float4*)(bias + cg * 8 + 4);
    float acc[4][8];
    #pragma unroll
    for (int rr = 0; rr < 4; ++rr) {
        acc[rr][0] = b0.x; acc[rr][1] = b0.y; acc[rr][2] = b0.z; acc[rr][3] = b0.w;
        acc[rr][4] = b1.x; acc[rr][5] = b1.y; acc[rr][6] = b1.z; acc[rr][7] = b1.w;
    }
    #pragma unroll 8
    for (int c = 0; c < 64; ++c) {
        float xr[4];
        #pragma unroll
        for (int rr = 0; rr < 4; ++rr) xr[rr] = xs[r0 + rr][c];
        float4 wA = *(const float4*)&ws[c][cg * 8];
        float4 wB = *(const float4*)&ws[c][cg * 8 + 4];
        float wv8[8] = {wA.x, wA.y, wA.z, wA.w, wB.x, wB.y, wB.z, wB.w};
        #pragma unroll
        for (int rr = 0; rr < 4; ++rr)
            #pragma unroll
            for (int cc = 0; cc < 8; ++cc)
                acc[rr][cc] += xr[rr] * wv8[cc];
    }
    #pragma unroll
    for (int rr = 0; rr < 4; ++rr) {
        int gr = row0 + r0 + rr;
        if (gr < NN) {
            float4 o0 = {acc[rr][0], acc[rr][1], acc[rr][2], acc[rr][3]};
            float4 o1 = {acc[rr][4], acc[rr][5], acc[rr][6], acc[rr][7]};
            *(float4*)(out + (size_t)gr * row_stride + cg * 8) = o0;
            *(float4*)(out + (size_t)gr * row_stride + cg * 8 + 4) = o1;
        }
    }
}

__device__ __forceinline__ void compute64(const float (*xs)[68], const float (*ws)[132],
                                          const float* __restrict__ bias,
                                          float* __restrict__ out, int row0, int t) {
    int rg = t >> 4, cg = t & 15;
    int r0 = rg * 4;
    float4 b0 = *(const float4*)(bias + cg * 4);
    float acc[4][4];
    #pragma unroll
    for (int rr = 0; rr < 4; ++rr) {
        acc[rr][0] = b0.x; acc[rr][1] = b0.y; acc[rr][2] = b0.z; acc[rr][3] = b0.w;
    }
    #pragma unroll 8
    for (int c = 0; c < 64; ++c) {
        float xr[4];
        #pragma unroll
        for (int rr = 0; rr < 4; ++rr) xr[rr] = xs[r0 + rr][c];
        float4 w = *(const float4*)&ws[c][cg * 4];
        float wv4[4] = {w.x, w.y, w.z, w.w};
        #pragma unroll
        for (int rr = 0; rr < 4; ++rr)
            #pragma unroll
            for (int cc = 0; cc < 4; ++cc)
                acc[rr][cc] += xr[rr] * wv4[cc];
    }
    #pragma unroll
    for (int rr = 0; rr < 4; ++rr) {
        int gr = row0 + r0 + rr;
        if (gr < NN) {
            float4 o0 = {acc[rr][0], acc[rr][1], acc[rr][2], acc[rr][3]};
            *(float4*)(out + (size_t)gr * 64 + cg * 4) = o0;
        }
    }
}

__global__ __launch_bounds__(256) void gemm_fused(const float* __restrict__ X,
    const float* __restrict__ Wq, const float* __restrict__ bq,
    const float* __restrict__ Wk, const float* __restrict__ bk,
    const float* __restrict__ Wv, const float* __restrict__ bv,
    const float* __restrict__ Wsk, const float* __restrict__ bsk,
    float* __restrict__ q, float* __restrict__ kv, float* __restrict__ skip) {
    __shared__ float xs[64][68];
    __shared__ float ws[64][132];
    int t = threadIdx.x;
    int row0 = blockIdx.x * 64;
    for (int i = t; i < 64 * 16; i += 256) {
        int r = i >> 4, c4 = i & 15;
        int gr = row0 + r;
        float4 val = make_float4(0.f, 0.f, 0.f, 0.f);
        if (gr < NN) val = *(const float4*)(X + (size_t)gr * 64 + c4 * 4);
        *(float4*)&xs[r][c4 * 4] = val;
    }
    const float* Wm[3] = {Wq, Wk, Wv};
    const float* bm[3] = {bq, bk, bv};
    float* om[3] = {q, kv, kv + 128};
    int strides[3] = {128, 256, 256};
    #pragma unroll 1
    for (int m = 0; m < 3; ++m) {
        __syncthreads();
        for (int i = t; i < 64 * 32; i += 256) {
            int r = i >> 5, c4 = i & 31;
            *(float4*)&ws[r][c4 * 4] = *(const float4*)(Wm[m] + r * 128 + c4 * 4);
        }
        __syncthreads();
        compute128(xs, ws, bm[m], om[m], strides[m], row0, t);
    }
    __syncthreads();
    for (int i = t; i < 64 * 16; i += 256) {
        int r = i >> 4, c4 = i & 15;
        *(float4*)&ws[r][c4 * 4] = *(const float4*)(Wsk + r * 64 + c4 * 4);
    }
    __syncthreads();
    compute64(xs, ws, bsk, skip, row0, t);
}

// ---------------- per-node attention aggregation (4-edge batched online softmax) ----------------
__global__ __launch_bounds__(256) void agg_kernel(
    const float* __restrict__ q, const float* __restrict__ kv,
    const float* __restrict__ skip,
    const int* __restrict__ rowst, const int* __restrict__ deg,
    const int* __restrict__ esrc, const float* __restrict__ gamma,
    const float* __restrict__ beta, float* __restrict__ hout, int do_ln) {
    int wave = threadIdx.x >> 6;
    int lane = threadIdx.x & 63;
    int node = blockIdx.x * 4 + wave;
    if (node >= NN) return;
    int j = lane & 15;
    int slot = lane >> 4;

    float4 q0 = *(const float4*)(q + (size_t)node * 128 + j * 4);
    float4 q1 = *(const float4*)(q + (size_t)node * 128 + 64 + j * 4);
    float m0 = -1e30f, m1 = -1e30f;
    float l0 = 0.f, l1 = 0.f;
    float acc0[4] = {0.f, 0.f, 0.f, 0.f};
    float acc1[4] = {0.f, 0.f, 0.f, 0.f};

    int st = rowst[node];
    int dg = deg[node];
    for (int base = slot * 4; base < dg; base += 16) {
        int last = dg - 1;
        int s0 = esrc[st + min(base + 0, last)];
        int s1 = esrc[st + min(base + 1, last)];
        int s2 = esrc[st + min(base + 2, last)];
        int s3 = esrc[st + min(base + 3, last)];
        const float* b0 = kv + (size_t)s0 * 256 + j * 4;
        const float* b1 = kv + (size_t)s1 * 256 + j * 4;
        const float* b2 = kv + (size_t)s2 * 256 + j * 4;
        const float* b3 = kv + (size_t)s3 * 256 + j * 4;
        float4 k00 = *(const float4*)(b0);
        float4 k01 = *(const float4*)(b0 + 64);
        float4 v00 = *(const float4*)(b0 + 128);
        float4 v01 = *(const float4*)(b0 + 192);
        float4 k10 = *(const float4*)(b1);
        float4 k11 = *(const float4*)(b1 + 64);
        float4 v10 = *(const float4*)(b1 + 128);
        float4 v11 = *(const float4*)(b1 + 192);
        float4 k20 = *(const float4*)(b2);
        float4 k21 = *(const float4*)(b2 + 64);
        float4 v20 = *(const float4*)(b2 + 128);
        float4 v21 = *(const float4*)(b2 + 192);
        float4 k30 = *(const float4*)(b3);
        float4 k31 = *(const float4*)(b3 + 64);
        float4 v30 = *(const float4*)(b3 + 128);
        float4 v31 = *(const float4*)(b3 + 192);

        float p00 = wave16_sum(dot4(q0, k00)) * 0.125f;
        float p01 = wave16_sum(dot4(q1, k01)) * 0.125f;
        float p10 = wave16_sum(dot4(q0, k10)) * 0.125f;
        float p11 = wave16_sum(dot4(q1, k11)) * 0.125f;
        float p20 = wave16_sum(dot4(q0, k20)) * 0.125f;
        float p21 = wave16_sum(dot4(q1, k21)) * 0.125f;
        float p30 = wave16_sum(dot4(q0, k30)) * 0.125f;
        float p31 = wave16_sum(dot4(q1, k31)) * 0.125f;
        // mask tail edges (uniform within the 16-lane slot group)
        if (base + 1 > last) { p10 = -1e30f; p11 = -1e30f; }
        if (base + 2 > last) { p20 = -1e30f; p21 = -1e30f; }
        if (base + 3 > last) { p30 = -1e30f; p31 = -1e30f; }
        // head 0: single batched rescale
        {
            float pm = fmaxf(fmaxf(p00, p10), fmaxf(p20, p30));
            float nm = fmaxf(m0, pm);
            float f = __expf(m0 - nm);
            float e0 = __expf(p00 - nm);
            float e1 = __expf(p10 - nm);
            float e2 = __expf(p20 - nm);
            float e3 = __expf(p30 - nm);
            l0 = l0 * f + (e0 + e1) + (e2 + e3);
            float va0[4] = {v00.x, v00.y, v00.z, v00.w};
            float va1[4] = {v10.x, v10.y, v10.z, v10.w};
            float va2[4] = {v20.x, v20.y, v20.z, v20.w};
            float va3[4] = {v30.x, v30.y, v30.z, v30.w};
            #pragma unroll
            for (int r = 0; r < 4; ++r)
                acc0[r] = acc0[r] * f + e0 * va0[r] + e1 * va1[r] + e2 * va2[r] + e3 * va3[r];
            m0 = nm;
        }
        // head 1
        {
            float pm = fmaxf(fmaxf(p01, p11), fmaxf(p21, p31));
            float nm = fmaxf(m1, pm);
            float f = __expf(m1 - nm);
            float e0 = __expf(p01 - nm);
            float e1 = __expf(p11 - nm);
            float e2 = __expf(p21 - nm);
            float e3 = __expf(p31 - nm);
            l1 = l1 * f + (e0 + e1) + (e2 + e3);
            float va0[4] = {v01.x, v01.y, v01.z, v01.w};
            float va1[4] = {v11.x, v11.y, v11.z, v11.w};
            float va2[4] = {v21.x, v21.y, v21.z, v21.w};
            float va3[4] = {v31.x, v31.y, v31.z, v31.w};
            #pragma unroll
            for (int r = 0; r < 4; ++r)
                acc1[r] = acc1[r] * f + e0 * va0[r] + e1 * va1[r] + e2 * va2[r] + e3 * va3[r];
            m1 = nm;
        }
    }
    // butterfly-merge the 4 slot states (masks 16, 32); exp(-1e30-x)=0 handles empties
    #pragma unroll
    for (int mask = 16; mask <= 32; mask <<= 1) {
        {
            float mo = __shfl_xor(m0, mask);
            float lo = __shfl_xor(l0, mask);
            float ao[4];
            #pragma unroll
            for (int r = 0; r < 4; ++r) ao[r] = __shfl_xor(acc0[r], mask);
            float nm = fmaxf(m0, mo);
            float fa = __expf(m0 - nm);
            float fb = __expf(mo - nm);
            l0 = l0 * fa + lo * fb;
            #pragma unroll
            for (int r = 0; r < 4; ++r) acc0[r] = acc0[r] * fa + ao[r] * fb;
            m0 = nm;
        }
        {
            float mo = __shfl_xor(m1, mask);
            float lo = __shfl_xor(l1, mask);
            float ao[4];
            #pragma unroll
            for (int r = 0; r < 4; ++r) ao[r] = __shfl_xor(acc1[r], mask);
            float nm = fmaxf(m1, mo);
            float fa = __expf(m1 - nm);
            float fb = __expf(mo - nm);
            l1 = l1 * fa + lo * fb;
            #pragma unroll
            for (int r = 0; r < 4; ++r) acc1[r] = acc1[r] * fa + ao[r] * fb;
            m1 = nm;
        }
    }
    float i0 = 1.f / (l0 + 1e-16f);
    float i1 = 1.f / (l1 + 1e-16f);
    float4 sk = *(const float4*)(skip + (size_t)node * 64 + j * 4);
    float ska[4] = {sk.x, sk.y, sk.z, sk.w};
    float val[4];
    #pragma unroll
    for (int r = 0; r < 4; ++r) {
        float o = 0.5f * (acc0[r] * i0 + acc1[r] * i1) + ska[r];
        val[r] = fmaxf(o, 0.f);
    }
    if (do_ln) {
        float s = val[0] + val[1] + val[2] + val[3];
        s = wave16_sum(s);
        float mu = s * (1.f / 64.f);
        float ss = 0.f;
        #pragma unroll
        for (int r = 0; r < 4; ++r) { float d = val[r] - mu; ss += d * d; }
        ss = wave16_sum(ss);
        float rstd = rsqrtf(ss * (1.f / 64.f) + 1e-5f);
        float4 g4 = *(const float4*)(gamma + j * 4);
        float4 b4 = *(const float4*)(beta + j * 4);
        float ga[4] = {g4.x, g4.y, g4.z, g4.w};
        float ba[4] = {b4.x, b4.y, b4.z, b4.w};
        #pragma unroll
        for (int r = 0; r < 4; ++r) val[r] = (val[r] - mu) * rstd * ga[r] + ba[r];
    }
    if (slot == 0) {
        float4 o; o.x = val[0]; o.y = val[1]; o.z = val[2]; o.w = val[3];
        *(float4*)(hout + (size_t)node * 64 + j * 4) = o;
    }
}

// ---------------- fused pool + final projection (batch is sorted) ----------------
__device__ __forceinline__ int lbound(const int* __restrict__ a, int n, int key) {
    int lo = 0, hi = n;
    while (lo < hi) {
        int mid = (lo + hi) >> 1;
        if (a[mid] < key) lo = mid + 1; else hi = mid;
    }
    return lo;
}

__global__ __launch_bounds__(256) void pool_final_kernel(
    const float* __restrict__ h, const int* __restrict__ batch,
    const float* __restrict__ Wout, const float* __restrict__ bout,
    float* __restrict__ out) {
    __shared__ int sh_lo, sh_hi;
    __shared__ float part[4][64];
    int g = blockIdx.x;
    int t = threadIdx.x;
    if (t == 0) {
        sh_lo = lbound(batch, NN, g);
        sh_hi = lbound(batch, NN, g + 1);
    }
    __syncthreads();
    int lo = sh_lo, hi = sh_hi;
    int c = t & 63, w = t >> 6;
    float s = 0.f;
    for (int n = lo + w; n < hi; n += 4) s += h[(size_t)n * 64 + c];
    part[w][c] = s;
    __syncthreads();
    if (t < 64) {
        float tot = part[0][t] + part[1][t] + part[2][t] + part[3][t];
        float cnt = (float)(hi - lo);
        float val = tot / fmaxf(cnt, 1.f) * Wout[t];
        #pragma unroll
        for (int mk = 1; mk < 64; mk <<= 1) val += __shfl_xor(val, mk);
        if (t == 0) out[g] = val + bout[0];
    }
}

extern "C" void kernel_launch(void* const* d_in, const int* in_sizes, int n_in,
                              void* d_out, int out_size, void* d_ws, size_t ws_size,
                              hipStream_t stream) {
    const float* x    = (const float*)d_in[0];
    const int*   ei   = (const int*)d_in[1];
    const int*   batch= (const int*)d_in[2];
    const float* Wq   = (const float*)d_in[4];
    const float* bq   = (const float*)d_in[5];
    const float* Wk   = (const float*)d_in[6];
    const float* bk   = (const float*)d_in[7];
    const float* Wv   = (const float*)d_in[8];
    const float* bv   = (const float*)d_in[9];
    const float* Ws   = (const float*)d_in[10];
    const float* bs   = (const float*)d_in[11];
    const float* lng  = (const float*)d_in[12];
    const float* lnb  = (const float*)d_in[13];
    const float* Wout = (const float*)d_in[14];
    const float* bout = (const float*)d_in[15];
    float* out = (float*)d_out;

    float* q    = (float*)d_ws;
    float* kv   = q + (size_t)NN * 128;
    float* skip = kv + (size_t)NN * 256;
    float* h0   = skip + (size_t)NN * 64;
    float* h1   = h0 + (size_t)NN * 64;
    int* deg    = (int*)(h1 + (size_t)NN * 64);
    int* rowst  = deg + NN;
    int* cursor = rowst + NN;
    int* bsum   = cursor + NN;
    int* esrc   = bsum + 256;

    hipMemsetAsync(deg, 0, NN * sizeof(int), stream);

    const int NB = (NN + 255) / 256;  // 196
    deg_kernel<<<(EE + 255) / 256, 256, 0, stream>>>(ei, deg);
    scan1<<<NB, 256, 0, stream>>>(deg, rowst, bsum);
    scan2<<<1, 256, 0, stream>>>(bsum, NB);
    scan3<<<NB, 256, 0, stream>>>(rowst, deg, bsum, cursor);
    fill_kernel<<<(EE + 255) / 256, 256, 0, stream>>>(ei, cursor, esrc);

    const int GEMM_GRID = (NN + 63) / 64;  // 782
    const float* hin = x;
    float* houts[3] = {h0, h1, h0};
    for (int l = 0; l < 3; ++l) {
        gemm_fused<<<GEMM_GRID, 256, 0, stream>>>(hin,
            Wq + (size_t)l * 64 * 128, bq + (size_t)l * 128,
            Wk + (size_t)l * 64 * 128, bk + (size_t)l * 128,
            Wv + (size_t)l * 64 * 128, bv + (size_t)l * 128,
            Ws + (size_t)l * 64 * 64, bs + (size_t)l * 64,
            q, kv, skip);
        int do_ln = (l < 2) ? 1 : 0;
        agg_kernel<<<(NN + 3) / 4, 256, 0, stream>>>(q, kv, skip, rowst, deg, esrc,
                                                     lng + (size_t)(do_ln ? l : 0) * 64,
                                                     lnb + (size_t)(do_ln ? l : 0) * 64,
                                                     houts[l], do_ln);
        hin = houts[l];
    }
    pool_final_kernel<<<GG, 256, 0, stream>>>(hin, batch, Wout, bout, out);
}

// Round 7
// 515.498 us; speedup vs baseline: 2.2917x; 1.2872x over previous
//
#include <hip/hip_runtime.h>
#include <hip/hip_fp16.h>
#include <math.h>

#define NN 50000
#define EE 800000
#define GG 512

__device__ __forceinline__ float wave16_sum(float p) {
    p += __shfl_xor(p, 1);
    p += __shfl_xor(p, 2);
    p += __shfl_xor(p, 4);
    p += __shfl_xor(p, 8);
    return p;
}
__device__ __forceinline__ float dot4(float4 a, float4 b) {
    return a.x * b.x + a.y * b.y + a.z * b.z + a.w * b.w;
}
__device__ __forceinline__ float2 h2f(unsigned int u) {
    __half2 h = *reinterpret_cast<__half2*>(&u);
    return __half22float2(h);
}
__device__ __forceinline__ unsigned short f2us(float x) {
    return __half_as_ushort(__float2half(x));
}

// ---------------- CSR build ----------------
__global__ void deg_kernel(const int* __restrict__ ei, int* __restrict__ deg) {
    int e = blockIdx.x * 256 + threadIdx.x;
    if (e < EE) atomicAdd(&deg[ei[EE + e]], 1);
}

__global__ void scan1(const int* __restrict__ deg, int* __restrict__ incl, int* __restrict__ bsum) {
    __shared__ int sh[256];
    int t = threadIdx.x;
    int n = blockIdx.x * 256 + t;
    int vv = (n < NN) ? deg[n] : 0;
    sh[t] = vv; __syncthreads();
    for (int off = 1; off < 256; off <<= 1) {
        int u = (t >= off) ? sh[t - off] : 0;
        __syncthreads();
        sh[t] += u;
        __syncthreads();
    }
    if (n < NN) incl[n] = sh[t];
    if (t == 255) bsum[blockIdx.x] = sh[255];
}

__global__ void scan2(int* __restrict__ bsum, int nblk) {
    __shared__ int sh[256];
    int t = threadIdx.x;
    int vv = (t < nblk) ? bsum[t] : 0;
    sh[t] = vv; __syncthreads();
    for (int off = 1; off < 256; off <<= 1) {
        int u = (t >= off) ? sh[t - off] : 0;
        __syncthreads();
        sh[t] += u;
        __syncthreads();
    }
    bsum[t] = sh[t];
}

__global__ void scan3(int* __restrict__ rowst, const int* __restrict__ deg,
                      const int* __restrict__ bsum, int* __restrict__ cursor) {
    int n = blockIdx.x * 256 + threadIdx.x;
    if (n >= NN) return;
    int off = (blockIdx.x > 0) ? bsum[blockIdx.x - 1] : 0;
    int excl = rowst[n] - deg[n] + off;
    rowst[n] = excl;
    cursor[n] = excl;
}

__global__ void fill_kernel(const int* __restrict__ ei, int* __restrict__ cursor,
                            int* __restrict__ esrc) {
    int e = blockIdx.x * 256 + threadIdx.x;
    if (e < EE) {
        int s = ei[e], d = ei[EE + e];
        int pos = atomicAdd(&cursor[d], 1);
        esrc[pos] = s;
    }
}

// ---------------- fused per-layer GEMM ----------------
// q: fp32 [NN][128]. kvh: fp16 [NN][256] lane-interleaved:
//   group j (0..15) holds halves [j*16, j*16+16): k0[j*4..+3], k1[...], v0[...], v1[...]
__device__ __forceinline__ void compute128_f32(const float (*xs)[68], const float (*ws)[132],
                                               const float* __restrict__ bias,
                                               float* __restrict__ out, int row0, int t) {
    int rg = t >> 4, cg = t & 15;
    int r0 = rg * 4;
    float4 b0 = *(const float4*)(bias + cg * 8);
    float4 b1 = *(const float4*)(bias + cg * 8 + 4);
    float acc[4][8];
    #pragma unroll
    for (int rr = 0; rr < 4; ++rr) {
        acc[rr][0] = b0.x; acc[rr][1] = b0.y; acc[rr][2] = b0.z; acc[rr][3] = b0.w;
        acc[rr][4] = b1.x; acc[rr][5] = b1.y; acc[rr][6] = b1.z; acc[rr][7] = b1.w;
    }
    #pragma unroll 8
    for (int c = 0; c < 64; ++c) {
        float xr[4];
        #pragma unroll
        for (int rr = 0; rr < 4; ++rr) xr[rr] = xs[r0 + rr][c];
        float4 wA = *(const float4*)&ws[c][cg * 8];
        float4 wB = *(const float4*)&ws[c][cg * 8 + 4];
        float wv8[8] = {wA.x, wA.y, wA.z, wA.w, wB.x, wB.y, wB.z, wB.w};
        #pragma unroll
        for (int rr = 0; rr < 4; ++rr)
            #pragma unroll
            for (int cc = 0; cc < 8; ++cc)
                acc[rr][cc] += xr[rr] * wv8[cc];
    }
    #pragma unroll
    for (int rr = 0; rr < 4; ++rr) {
        int gr = row0 + r0 + rr;
        if (gr < NN) {
            float4 o0 = {acc[rr][0], acc[rr][1], acc[rr][2], acc[rr][3]};
            float4 o1 = {acc[rr][4], acc[rr][5], acc[rr][6], acc[rr][7]};
            *(float4*)(out + (size_t)gr * 128 + cg * 8) = o0;
            *(float4*)(out + (size_t)gr * 128 + cg * 8 + 4) = o1;
        }
    }
}

__device__ __forceinline__ void compute128_h16(const float (*xs)[68], const float (*ws)[132],
                                               const float* __restrict__ bias,
                                               unsigned short* __restrict__ kvh,
                                               int vofs, int row0, int t) {
    int rg = t >> 4, cg = t & 15;
    int r0 = rg * 4;
    float4 b0 = *(const float4*)(bias + cg * 8);
    float4 b1 = *(const float4*)(bias + cg * 8 + 4);
    float acc[4][8];
    #pragma unroll
    for (int rr = 0; rr < 4; ++rr) {
        acc[rr][0] = b0.x; acc[rr][1] = b0.y; acc[rr][2] = b0.z; acc[rr][3] = b0.w;
        acc[rr][4] = b1.x; acc[rr][5] = b1.y; acc[rr][6] = b1.z; acc[rr][7] = b1.w;
    }
    #pragma unroll 8
    for (int c = 0; c < 64; ++c) {
        float xr[4];
        #pragma unroll
        for (int rr = 0; rr < 4; ++rr) xr[rr] = xs[r0 + rr][c];
        float4 wA = *(const float4*)&ws[c][cg * 8];
        float4 wB = *(const float4*)&ws[c][cg * 8 + 4];
        float wv8[8] = {wA.x, wA.y, wA.z, wA.w, wB.x, wB.y, wB.z, wB.w};
        #pragma unroll
        for (int rr = 0; rr < 4; ++rr)
            #pragma unroll
            for (int cc = 0; cc < 8; ++cc)
                acc[rr][cc] += xr[rr] * wv8[cc];
    }
    // cols cg*8..cg*8+7: head = cg>>3, local col = (cg&7)*8 + cc
    // dest half-offset = group*16 + head*4 + (cc&3) + vofs, group = (cg&7)*2 + (cc>>2)
    int head = cg >> 3;
    int off = ((cg & 7) * 2) * 16 + head * 4 + vofs;
    #pragma unroll
    for (int rr = 0; rr < 4; ++rr) {
        int gr = row0 + r0 + rr;
        if (gr < NN) {
            ushort4 pa = make_ushort4(f2us(acc[rr][0]), f2us(acc[rr][1]),
                                      f2us(acc[rr][2]), f2us(acc[rr][3]));
            ushort4 pb = make_ushort4(f2us(acc[rr][4]), f2us(acc[rr][5]),
                                      f2us(acc[rr][6]), f2us(acc[rr][7]));
            *(ushort4*)(kvh + (size_t)gr * 256 + off) = pa;
            *(ushort4*)(kvh + (size_t)gr * 256 + off + 16) = pb;
        }
    }
}

__device__ __forceinline__ void compute64(const float (*xs)[68], const float (*ws)[132],
                                          const float* __restrict__ bias,
                                          float* __restrict__ out, int row0, int t) {
    int rg = t >> 4, cg = t & 15;
    int r0 = rg * 4;
    float4 b0 = *(const float4*)(bias + cg * 4);
    float acc[4][4];
    #pragma unroll
    for (int rr = 0; rr < 4; ++rr) {
        acc[rr][0] = b0.x; acc[rr][1] = b0.y; acc[rr][2] = b0.z; acc[rr][3] = b0.w;
    }
    #pragma unroll 8
    for (int c = 0; c < 64; ++c) {
        float xr[4];
        #pragma unroll
        for (int rr = 0; rr < 4; ++rr) xr[rr] = xs[r0 + rr][c];
        float4 w = *(const float4*)&ws[c][cg * 4];
        float wv4[4] = {w.x, w.y, w.z, w.w};
        #pragma unroll
        for (int rr = 0; rr < 4; ++rr)
            #pragma unroll
            for (int cc = 0; cc < 4; ++cc)
                acc[rr][cc] += xr[rr] * wv4[cc];
    }
    #pragma unroll
    for (int rr = 0; rr < 4; ++rr) {
        int gr = row0 + r0 + rr;
        if (gr < NN) {
            float4 o0 = {acc[rr][0], acc[rr][1], acc[rr][2], acc[rr][3]};
            *(float4*)(out + (size_t)gr * 64 + cg * 4) = o0;
        }
    }
}

__global__ __launch_bounds__(256) void gemm_fused(const float* __restrict__ X,
    const float* __restrict__ Wq, const float* __restrict__ bq,
    const float* __restrict__ Wk, const float* __restrict__ bk,
    const float* __restrict__ Wv, const float* __restrict__ bv,
    const float* __restrict__ Wsk, const float* __restrict__ bsk,
    float* __restrict__ q, unsigned short* __restrict__ kvh, float* __restrict__ skip) {
    __shared__ float xs[64][68];
    __shared__ float ws[64][132];
    int t = threadIdx.x;
    int row0 = blockIdx.x * 64;
    for (int i = t; i < 64 * 16; i += 256) {
        int r = i >> 4, c4 = i & 15;
        int gr = row0 + r;
        float4 val = make_float4(0.f, 0.f, 0.f, 0.f);
        if (gr < NN) val = *(const float4*)(X + (size_t)gr * 64 + c4 * 4);
        *(float4*)&xs[r][c4 * 4] = val;
    }
    const float* Wm[3] = {Wq, Wk, Wv};
    const float* bm[3] = {bq, bk, bv};
    #pragma unroll 1
    for (int m = 0; m < 3; ++m) {
        __syncthreads();
        for (int i = t; i < 64 * 32; i += 256) {
            int r = i >> 5, c4 = i & 31;
            *(float4*)&ws[r][c4 * 4] = *(const float4*)(Wm[m] + r * 128 + c4 * 4);
        }
        __syncthreads();
        if (m == 0) compute128_f32(xs, ws, bm[m], q, row0, t);
        else        compute128_h16(xs, ws, bm[m], kvh, (m == 2) ? 8 : 0, row0, t);
    }
    __syncthreads();
    for (int i = t; i < 64 * 16; i += 256) {
        int r = i >> 4, c4 = i & 15;
        *(float4*)&ws[r][c4 * 4] = *(const float4*)(Wsk + r * 64 + c4 * 4);
    }
    __syncthreads();
    compute64(xs, ws, bsk, skip, row0, t);
}

// ---------------- per-node attention aggregation (fp16 kv gather) ----------------
__global__ __launch_bounds__(256) void agg_kernel(
    const float* __restrict__ q, const unsigned short* __restrict__ kvh,
    const float* __restrict__ skip,
    const int* __restrict__ rowst, const int* __restrict__ deg,
    const int* __restrict__ esrc, const float* __restrict__ gamma,
    const float* __restrict__ beta, float* __restrict__ hout, int do_ln) {
    int wave = threadIdx.x >> 6;
    int lane = threadIdx.x & 63;
    int node = blockIdx.x * 4 + wave;
    if (node >= NN) return;
    int j = lane & 15;
    int slot = lane >> 4;

    float4 q0 = *(const float4*)(q + (size_t)node * 128 + j * 4);
    float4 q1 = *(const float4*)(q + (size_t)node * 128 + 64 + j * 4);
    float m0 = -1e30f, m1 = -1e30f;
    float l0 = 0.f, l1 = 0.f;
    float acc0[4] = {0.f, 0.f, 0.f, 0.f};
    float acc1[4] = {0.f, 0.f, 0.f, 0.f};

    int st = rowst[node];
    int dg = deg[node];
    for (int base = slot * 2; base < dg; base += 8) {
        int last = dg - 1;
        int s0 = esrc[st + min(base + 0, last)];
        int s1 = esrc[st + min(base + 1, last)];
        const unsigned short* b0 = kvh + (size_t)s0 * 256 + j * 16;
        const unsigned short* b1 = kvh + (size_t)s1 * 256 + j * 16;
        uint4 A0 = *(const uint4*)(b0);       // k0[4],k1[4]
        uint4 B0 = *(const uint4*)(b0 + 8);   // v0[4],v1[4]
        uint4 A1 = *(const uint4*)(b1);
        uint4 B1 = *(const uint4*)(b1 + 8);

        float2 a00 = h2f(A0.x), a01 = h2f(A0.y), a02 = h2f(A0.z), a03 = h2f(A0.w);
        float2 a10 = h2f(A1.x), a11 = h2f(A1.y), a12 = h2f(A1.z), a13 = h2f(A1.w);
        float4 k00 = {a00.x, a00.y, a01.x, a01.y};
        float4 k01 = {a02.x, a02.y, a03.x, a03.y};
        float4 k10 = {a10.x, a10.y, a11.x, a11.y};
        float4 k11 = {a12.x, a12.y, a13.x, a13.y};

        float p00 = wave16_sum(dot4(q0, k00)) * 0.125f;
        float p01 = wave16_sum(dot4(q1, k01)) * 0.125f;
        float p10 = wave16_sum(dot4(q0, k10)) * 0.125f;
        float p11 = wave16_sum(dot4(q1, k11)) * 0.125f;
        if (base + 1 > last) { p10 = -1e30f; p11 = -1e30f; }

        float2 c00 = h2f(B0.x), c01 = h2f(B0.y), c02 = h2f(B0.z), c03 = h2f(B0.w);
        float2 c10 = h2f(B1.x), c11 = h2f(B1.y), c12 = h2f(B1.z), c13 = h2f(B1.w);
        float v00[4] = {c00.x, c00.y, c01.x, c01.y};
        float v01[4] = {c02.x, c02.y, c03.x, c03.y};
        float v10[4] = {c10.x, c10.y, c11.x, c11.y};
        float v11[4] = {c12.x, c12.y, c13.x, c13.y};

        {
            float nm = fmaxf(m0, fmaxf(p00, p10));
            float f = __expf(m0 - nm);
            float e0 = __expf(p00 - nm);
            float e1 = __expf(p10 - nm);
            l0 = l0 * f + e0 + e1;
            #pragma unroll
            for (int r = 0; r < 4; ++r)
                acc0[r] = acc0[r] * f + e0 * v00[r] + e1 * v10[r];
            m0 = nm;
        }
        {
            float nm = fmaxf(m1, fmaxf(p01, p11));
            float f = __expf(m1 - nm);
            float e0 = __expf(p01 - nm);
            float e1 = __expf(p11 - nm);
            l1 = l1 * f + e0 + e1;
            #pragma unroll
            for (int r = 0; r < 4; ++r)
                acc1[r] = acc1[r] * f + e0 * v01[r] + e1 * v11[r];
            m1 = nm;
        }
    }
    // butterfly-merge the 4 slot states (masks 16, 32)
    #pragma unroll
    for (int mask = 16; mask <= 32; mask <<= 1) {
        {
            float mo = __shfl_xor(m0, mask);
            float lo = __shfl_xor(l0, mask);
            float ao[4];
            #pragma unroll
            for (int r = 0; r < 4; ++r) ao[r] = __shfl_xor(acc0[r], mask);
            float nm = fmaxf(m0, mo);
            float fa = __expf(m0 - nm);
            float fb = __expf(mo - nm);
            l0 = l0 * fa + lo * fb;
            #pragma unroll
            for (int r = 0; r < 4; ++r) acc0[r] = acc0[r] * fa + ao[r] * fb;
            m0 = nm;
        }
        {
            float mo = __shfl_xor(m1, mask);
            float lo = __shfl_xor(l1, mask);
            float ao[4];
            #pragma unroll
            for (int r = 0; r < 4; ++r) ao[r] = __shfl_xor(acc1[r], mask);
            float nm = fmaxf(m1, mo);
            float fa = __expf(m1 - nm);
            float fb = __expf(mo - nm);
            l1 = l1 * fa + lo * fb;
            #pragma unroll
            for (int r = 0; r < 4; ++r) acc1[r] = acc1[r] * fa + ao[r] * fb;
            m1 = nm;
        }
    }
    float i0 = 1.f / (l0 + 1e-16f);
    float i1 = 1.f / (l1 + 1e-16f);
    float4 sk = *(const float4*)(skip + (size_t)node * 64 + j * 4);
    float ska[4] = {sk.x, sk.y, sk.z, sk.w};
    float val[4];
    #pragma unroll
    for (int r = 0; r < 4; ++r) {
        float o = 0.5f * (acc0[r] * i0 + acc1[r] * i1) + ska[r];
        val[r] = fmaxf(o, 0.f);
    }
    if (do_ln) {
        float s = val[0] + val[1] + val[2] + val[3];
        s = wave16_sum(s);
        float mu = s * (1.f / 64.f);
        float ss = 0.f;
        #pragma unroll
        for (int r = 0; r < 4; ++r) { float d = val[r] - mu; ss += d * d; }
        ss = wave16_sum(ss);
        float rstd = rsqrtf(ss * (1.f / 64.f) + 1e-5f);
        float4 g4 = *(const float4*)(gamma + j * 4);
        float4 b4 = *(const float4*)(beta + j * 4);
        float ga[4] = {g4.x, g4.y, g4.z, g4.w};
        float ba[4] = {b4.x, b4.y, b4.z, b4.w};
        #pragma unroll
        for (int r = 0; r < 4; ++r) val[r] = (val[r] - mu) * rstd * ga[r] + ba[r];
    }
    if (slot == 0) {
        float4 o; o.x = val[0]; o.y = val[1]; o.z = val[2]; o.w = val[3];
        *(float4*)(hout + (size_t)node * 64 + j * 4) = o;
    }
}

// ---------------- fused pool + final projection (batch is sorted) ----------------
__device__ __forceinline__ int lbound(const int* __restrict__ a, int n, int key) {
    int lo = 0, hi = n;
    while (lo < hi) {
        int mid = (lo + hi) >> 1;
        if (a[mid] < key) lo = mid + 1; else hi = mid;
    }
    return lo;
}

__global__ __launch_bounds__(256) void pool_final_kernel(
    const float* __restrict__ h, const int* __restrict__ batch,
    const float* __restrict__ Wout, const float* __restrict__ bout,
    float* __restrict__ out) {
    __shared__ int sh_lo, sh_hi;
    __shared__ float part[4][64];
    int g = blockIdx.x;
    int t = threadIdx.x;
    if (t == 0) {
        sh_lo = lbound(batch, NN, g);
        sh_hi = lbound(batch, NN, g + 1);
    }
    __syncthreads();
    int lo = sh_lo, hi = sh_hi;
    int c = t & 63, w = t >> 6;
    float s = 0.f;
    for (int n = lo + w; n < hi; n += 4) s += h[(size_t)n * 64 + c];
    part[w][c] = s;
    __syncthreads();
    if (t < 64) {
        float tot = part[0][t] + part[1][t] + part[2][t] + part[3][t];
        float cnt = (float)(hi - lo);
        float val = tot / fmaxf(cnt, 1.f) * Wout[t];
        #pragma unroll
        for (int mk = 1; mk < 64; mk <<= 1) val += __shfl_xor(val, mk);
        if (t == 0) out[g] = val + bout[0];
    }
}

extern "C" void kernel_launch(void* const* d_in, const int* in_sizes, int n_in,
                              void* d_out, int out_size, void* d_ws, size_t ws_size,
                              hipStream_t stream) {
    const float* x    = (const float*)d_in[0];
    const int*   ei   = (const int*)d_in[1];
    const int*   batch= (const int*)d_in[2];
    const float* Wq   = (const float*)d_in[4];
    const float* bq   = (const float*)d_in[5];
    const float* Wk   = (const float*)d_in[6];
    const float* bk   = (const float*)d_in[7];
    const float* Wv   = (const float*)d_in[8];
    const float* bv   = (const float*)d_in[9];
    const float* Ws   = (const float*)d_in[10];
    const float* bs   = (const float*)d_in[11];
    const float* lng  = (const float*)d_in[12];
    const float* lnb  = (const float*)d_in[13];
    const float* Wout = (const float*)d_in[14];
    const float* bout = (const float*)d_in[15];
    float* out = (float*)d_out;

    float* q    = (float*)d_ws;
    unsigned short* kvh = (unsigned short*)(q + (size_t)NN * 128);
    float* skip = (float*)(kvh + (size_t)NN * 256);
    float* h0   = skip + (size_t)NN * 64;
    float* h1   = h0 + (size_t)NN * 64;
    int* deg    = (int*)(h1 + (size_t)NN * 64);
    int* rowst  = deg + NN;
    int* cursor = rowst + NN;
    int* bsum   = cursor + NN;
    int* esrc   = bsum + 256;

    hipMemsetAsync(deg, 0, NN * sizeof(int), stream);

    const int NB = (NN + 255) / 256;  // 196
    deg_kernel<<<(EE + 255) / 256, 256, 0, stream>>>(ei, deg);
    scan1<<<NB, 256, 0, stream>>>(deg, rowst, bsum);
    scan2<<<1, 256, 0, stream>>>(bsum, NB);
    scan3<<<NB, 256, 0, stream>>>(rowst, deg, bsum, cursor);
    fill_kernel<<<(EE + 255) / 256, 256, 0, stream>>>(ei, cursor, esrc);

    const int GEMM_GRID = (NN + 63) / 64;  // 782
    const float* hin = x;
    float* houts[3] = {h0, h1, h0};
    for (int l = 0; l < 3; ++l) {
        gemm_fused<<<GEMM_GRID, 256, 0, stream>>>(hin,
            Wq + (size_t)l * 64 * 128, bq + (size_t)l * 128,
            Wk + (size_t)l * 64 * 128, bk + (size_t)l * 128,
            Wv + (size_t)l * 64 * 128, bv + (size_t)l * 128,
            Ws + (size_t)l * 64 * 64, bs + (size_t)l * 64,
            q, kvh, skip);
        int do_ln = (l < 2) ? 1 : 0;
        agg_kernel<<<(NN + 3) / 4, 256, 0, stream>>>(q, kvh, skip, rowst, deg, esrc,
                                                     lng + (size_t)(do_ln ? l : 0) * 64,
                                                     lnb + (size_t)(do_ln ? l : 0) * 64,
                                                     houts[l], do_ln);
        hin = houts[l];
    }
    pool_final_kernel<<<GG, 256, 0, stream>>>(hin, batch, Wout, bout, out);
}

// Round 8
// 417.935 us; speedup vs baseline: 2.8266x; 1.2334x over previous
//
#include <hip/hip_runtime.h>
#include <hip/hip_fp16.h>
#include <math.h>

#define NN 50000
#define EE 800000
#define GG 512

typedef _Float16 f16x8 __attribute__((ext_vector_type(8)));
typedef float f32x4 __attribute__((ext_vector_type(4)));

__device__ __forceinline__ float wave16_sum(float p) {
    p += __shfl_xor(p, 1);
    p += __shfl_xor(p, 2);
    p += __shfl_xor(p, 4);
    p += __shfl_xor(p, 8);
    return p;
}
__device__ __forceinline__ float dot4(float4 a, float4 b) {
    return a.x * b.x + a.y * b.y + a.z * b.z + a.w * b.w;
}
__device__ __forceinline__ float2 h2f(unsigned int u) {
    __half2 h = *reinterpret_cast<__half2*>(&u);
    return __half22float2(h);
}
__device__ __forceinline__ unsigned short f2us(float x) {
    return __half_as_ushort(__float2half(x));
}
__device__ __forceinline__ float us2f(unsigned short u) {
    return __half2float(__ushort_as_half(u));
}

// ---------------- CSR build ----------------
__global__ void deg_kernel(const int* __restrict__ ei, int* __restrict__ deg) {
    int e = blockIdx.x * 256 + threadIdx.x;
    if (e < EE) atomicAdd(&deg[ei[EE + e]], 1);
}

__global__ void scan1(const int* __restrict__ deg, int* __restrict__ incl, int* __restrict__ bsum) {
    __shared__ int sh[256];
    int t = threadIdx.x;
    int n = blockIdx.x * 256 + t;
    int vv = (n < NN) ? deg[n] : 0;
    sh[t] = vv; __syncthreads();
    for (int off = 1; off < 256; off <<= 1) {
        int u = (t >= off) ? sh[t - off] : 0;
        __syncthreads();
        sh[t] += u;
        __syncthreads();
    }
    if (n < NN) incl[n] = sh[t];
    if (t == 255) bsum[blockIdx.x] = sh[255];
}

__global__ void scan2(int* __restrict__ bsum, int nblk) {
    __shared__ int sh[256];
    int t = threadIdx.x;
    int vv = (t < nblk) ? bsum[t] : 0;
    sh[t] = vv; __syncthreads();
    for (int off = 1; off < 256; off <<= 1) {
        int u = (t >= off) ? sh[t - off] : 0;
        __syncthreads();
        sh[t] += u;
        __syncthreads();
    }
    bsum[t] = sh[t];
}

__global__ void scan3(int* __restrict__ rowst, const int* __restrict__ deg,
                      const int* __restrict__ bsum, int* __restrict__ cursor) {
    int n = blockIdx.x * 256 + threadIdx.x;
    if (n >= NN) return;
    int off = (blockIdx.x > 0) ? bsum[blockIdx.x - 1] : 0;
    int excl = rowst[n] - deg[n] + off;
    rowst[n] = excl;
    cursor[n] = excl;
}

__global__ void fill_kernel(const int* __restrict__ ei, int* __restrict__ cursor,
                            int* __restrict__ esrc) {
    int e = blockIdx.x * 256 + threadIdx.x;
    if (e < EE) {
        int s = ei[e], d = ei[EE + e];
        int pos = atomicAdd(&cursor[d], 1);
        esrc[pos] = s;
    }
}

// ---------------- precompute: fp16 casts ----------------
__global__ void cast_x_kernel(const float* __restrict__ x, unsigned short* __restrict__ xh) {
    int i = blockIdx.x * 256 + threadIdx.x;
    if (i < NN * 16) {
        float4 v = *(const float4*)(x + (size_t)i * 4);
        ushort4 o = make_ushort4(f2us(v.x), f2us(v.y), f2us(v.z), f2us(v.w));
        *(ushort4*)(xh + (size_t)i * 4) = o;
    }
}

// wt layout per layer: [448][64] fp16, wt[c][k] = W[k][c]; c: 0..127 q, 128..255 k, 256..383 v, 384..447 skip
#define WT_LSTRIDE (448 * 64)
__global__ void pack_w_kernel(const float* __restrict__ Wq, const float* __restrict__ Wk,
                              const float* __restrict__ Wv, const float* __restrict__ Ws,
                              unsigned short* __restrict__ wt) {
    int idx = blockIdx.x * 256 + threadIdx.x;
    if (idx >= 3 * WT_LSTRIDE) return;
    int l = idx / WT_LSTRIDE, r = idx % WT_LSTRIDE;
    int c = r / 64, k = r % 64;
    float val;
    if (c < 384) {
        int m = c >> 7, col = c & 127;
        const float* W = (m == 0) ? Wq : ((m == 1) ? Wk : Wv);
        val = W[(size_t)l * 64 * 128 + k * 128 + col];
    } else {
        int col = c - 384;
        val = Ws[(size_t)l * 64 * 64 + k * 64 + col];
    }
    wt[idx] = f2us(val);
}

// ---------------- MFMA GEMM: [NN x 64] fp16 @ [64 x 448] fp16 -> q(f32), kvh(f16), skip(f32) ----------------
__global__ __launch_bounds__(256) void gemm_mfma(
    const unsigned short* __restrict__ xh,
    const unsigned short* __restrict__ wt,
    const float* __restrict__ bq, const float* __restrict__ bk,
    const float* __restrict__ bv, const float* __restrict__ bsk,
    float* __restrict__ q, unsigned short* __restrict__ kvh,
    float* __restrict__ skip) {
    int t = threadIdx.x;
    int wave = t >> 6, lane = t & 63;
    int li = lane & 15, lh = lane >> 4;
    int row0 = blockIdx.x * 32 + (wave & 1) * 16;
    int ctbase = (wave >> 1) * 14;

    int arow = min(row0 + li, NN - 1);
    const unsigned short* ap = xh + (size_t)arow * 64 + lh * 8;
    f16x8 a0 = *(const f16x8*)(ap);
    f16x8 a1 = *(const f16x8*)(ap + 32);

    int rb = row0 + lh * 4;

    #pragma unroll 2
    for (int tt = 0; tt < 14; ++tt) {
        int c = (ctbase + tt) * 16 + li;
        const unsigned short* bp = wt + (size_t)c * 64 + lh * 8;
        f16x8 b0 = *(const f16x8*)(bp);
        f16x8 b1 = *(const f16x8*)(bp + 32);
        f32x4 d = {0.f, 0.f, 0.f, 0.f};
        d = __builtin_amdgcn_mfma_f32_16x16x32_f16(a0, b0, d, 0, 0, 0);
        d = __builtin_amdgcn_mfma_f32_16x16x32_f16(a1, b1, d, 0, 0, 0);
        if (c < 128) {
            float bias = bq[c];
            #pragma unroll
            for (int e = 0; e < 4; ++e) {
                int r = rb + e;
                if (r < NN) q[(size_t)r * 128 + c] = d[e] + bias;
            }
        } else if (c < 256) {
            int ch = c - 128;
            float bias = bk[ch];
            int off = (ch < 64) ? ((ch >> 2) * 16 + (ch & 3))
                                : (((ch - 64) >> 2) * 16 + 4 + (ch & 3));
            #pragma unroll
            for (int e = 0; e < 4; ++e) {
                int r = rb + e;
                if (r < NN) kvh[(size_t)r * 256 + off] = f2us(d[e] + bias);
            }
        } else if (c < 384) {
            int ch = c - 256;
            float bias = bv[ch];
            int off = 8 + ((ch < 64) ? ((ch >> 2) * 16 + (ch & 3))
                                     : (((ch - 64) >> 2) * 16 + 4 + (ch & 3)));
            #pragma unroll
            for (int e = 0; e < 4; ++e) {
                int r = rb + e;
                if (r < NN) kvh[(size_t)r * 256 + off] = f2us(d[e] + bias);
            }
        } else {
            int ch = c - 384;
            float bias = bsk[ch];
            #pragma unroll
            for (int e = 0; e < 4; ++e) {
                int r = rb + e;
                if (r < NN) skip[(size_t)r * 64 + ch] = d[e] + bias;
            }
        }
    }
}

// ---------------- per-node attention aggregation (fp16 kv gather) ----------------
__global__ __launch_bounds__(256) void agg_kernel(
    const float* __restrict__ q, const unsigned short* __restrict__ kvh,
    const float* __restrict__ skip,
    const int* __restrict__ rowst, const int* __restrict__ deg,
    const int* __restrict__ esrc, const float* __restrict__ gamma,
    const float* __restrict__ beta, unsigned short* __restrict__ hout, int do_ln) {
    int wave = threadIdx.x >> 6;
    int lane = threadIdx.x & 63;
    int node = blockIdx.x * 4 + wave;
    if (node >= NN) return;
    int j = lane & 15;
    int slot = lane >> 4;

    float4 q0 = *(const float4*)(q + (size_t)node * 128 + j * 4);
    float4 q1 = *(const float4*)(q + (size_t)node * 128 + 64 + j * 4);
    float m0 = -1e30f, m1 = -1e30f;
    float l0 = 0.f, l1 = 0.f;
    float acc0[4] = {0.f, 0.f, 0.f, 0.f};
    float acc1[4] = {0.f, 0.f, 0.f, 0.f};

    int st = rowst[node];
    int dg = deg[node];
    for (int base = slot * 2; base < dg; base += 8) {
        int last = dg - 1;
        int s0 = esrc[st + min(base + 0, last)];
        int s1 = esrc[st + min(base + 1, last)];
        const unsigned short* b0 = kvh + (size_t)s0 * 256 + j * 16;
        const unsigned short* b1 = kvh + (size_t)s1 * 256 + j * 16;
        uint4 A0 = *(const uint4*)(b0);       // k0[4],k1[4]
        uint4 B0 = *(const uint4*)(b0 + 8);   // v0[4],v1[4]
        uint4 A1 = *(const uint4*)(b1);
        uint4 B1 = *(const uint4*)(b1 + 8);

        float2 a00 = h2f(A0.x), a01 = h2f(A0.y), a02 = h2f(A0.z), a03 = h2f(A0.w);
        float2 a10 = h2f(A1.x), a11 = h2f(A1.y), a12 = h2f(A1.z), a13 = h2f(A1.w);
        float4 k00 = {a00.x, a00.y, a01.x, a01.y};
        float4 k01 = {a02.x, a02.y, a03.x, a03.y};
        float4 k10 = {a10.x, a10.y, a11.x, a11.y};
        float4 k11 = {a12.x, a12.y, a13.x, a13.y};

        float p00 = wave16_sum(dot4(q0, k00)) * 0.125f;
        float p01 = wave16_sum(dot4(q1, k01)) * 0.125f;
        float p10 = wave16_sum(dot4(q0, k10)) * 0.125f;
        float p11 = wave16_sum(dot4(q1, k11)) * 0.125f;
        if (base + 1 > last) { p10 = -1e30f; p11 = -1e30f; }

        float2 c00 = h2f(B0.x), c01 = h2f(B0.y), c02 = h2f(B0.z), c03 = h2f(B0.w);
        float2 c10 = h2f(B1.x), c11 = h2f(B1.y), c12 = h2f(B1.z), c13 = h2f(B1.w);
        float v00[4] = {c00.x, c00.y, c01.x, c01.y};
        float v01[4] = {c02.x, c02.y, c03.x, c03.y};
        float v10[4] = {c10.x, c10.y, c11.x, c11.y};
        float v11[4] = {c12.x, c12.y, c13.x, c13.y};

        {
            float nm = fmaxf(m0, fmaxf(p00, p10));
            float f = __expf(m0 - nm);
            float e0 = __expf(p00 - nm);
            float e1 = __expf(p10 - nm);
            l0 = l0 * f + e0 + e1;
            #pragma unroll
            for (int r = 0; r < 4; ++r)
                acc0[r] = acc0[r] * f + e0 * v00[r] + e1 * v10[r];
            m0 = nm;
        }
        {
            float nm = fmaxf(m1, fmaxf(p01, p11));
            float f = __expf(m1 - nm);
            float e0 = __expf(p01 - nm);
            float e1 = __expf(p11 - nm);
            l1 = l1 * f + e0 + e1;
            #pragma unroll
            for (int r = 0; r < 4; ++r)
                acc1[r] = acc1[r] * f + e0 * v01[r] + e1 * v11[r];
            m1 = nm;
        }
    }
    // butterfly-merge the 4 slot states (masks 16, 32)
    #pragma unroll
    for (int mask = 16; mask <= 32; mask <<= 1) {
        {
            float mo = __shfl_xor(m0, mask);
            float lo = __shfl_xor(l0, mask);
            float ao[4];
            #pragma unroll
            for (int r = 0; r < 4; ++r) ao[r] = __shfl_xor(acc0[r], mask);
            float nm = fmaxf(m0, mo);
            float fa = __expf(m0 - nm);
            float fb = __expf(mo - nm);
            l0 = l0 * fa + lo * fb;
            #pragma unroll
            for (int r = 0; r < 4; ++r) acc0[r] = acc0[r] * fa + ao[r] * fb;
            m0 = nm;
        }
        {
            float mo = __shfl_xor(m1, mask);
            float lo = __shfl_xor(l1, mask);
            float ao[4];
            #pragma unroll
            for (int r = 0; r < 4; ++r) ao[r] = __shfl_xor(acc1[r], mask);
            float nm = fmaxf(m1, mo);
            float fa = __expf(m1 - nm);
            float fb = __expf(mo - nm);
            l1 = l1 * fa + lo * fb;
            #pragma unroll
            for (int r = 0; r < 4; ++r) acc1[r] = acc1[r] * fa + ao[r] * fb;
            m1 = nm;
        }
    }
    float i0 = 1.f / (l0 + 1e-16f);
    float i1 = 1.f / (l1 + 1e-16f);
    float4 sk = *(const float4*)(skip + (size_t)node * 64 + j * 4);
    float ska[4] = {sk.x, sk.y, sk.z, sk.w};
    float val[4];
    #pragma unroll
    for (int r = 0; r < 4; ++r) {
        float o = 0.5f * (acc0[r] * i0 + acc1[r] * i1) + ska[r];
        val[r] = fmaxf(o, 0.f);
    }
    if (do_ln) {
        float s = val[0] + val[1] + val[2] + val[3];
        s = wave16_sum(s);
        float mu = s * (1.f / 64.f);
        float ss = 0.f;
        #pragma unroll
        for (int r = 0; r < 4; ++r) { float d = val[r] - mu; ss += d * d; }
        ss = wave16_sum(ss);
        float rstd = rsqrtf(ss * (1.f / 64.f) + 1e-5f);
        float4 g4 = *(const float4*)(gamma + j * 4);
        float4 b4 = *(const float4*)(beta + j * 4);
        float ga[4] = {g4.x, g4.y, g4.z, g4.w};
        float ba[4] = {b4.x, b4.y, b4.z, b4.w};
        #pragma unroll
        for (int r = 0; r < 4; ++r) val[r] = (val[r] - mu) * rstd * ga[r] + ba[r];
    }
    if (slot == 0) {
        ushort4 o = make_ushort4(f2us(val[0]), f2us(val[1]), f2us(val[2]), f2us(val[3]));
        *(ushort4*)(hout + (size_t)node * 64 + j * 4) = o;
    }
}

// ---------------- fused pool + final projection (batch is sorted) ----------------
__device__ __forceinline__ int lbound(const int* __restrict__ a, int n, int key) {
    int lo = 0, hi = n;
    while (lo < hi) {
        int mid = (lo + hi) >> 1;
        if (a[mid] < key) lo = mid + 1; else hi = mid;
    }
    return lo;
}

__global__ __launch_bounds__(256) void pool_final_kernel(
    const unsigned short* __restrict__ h, const int* __restrict__ batch,
    const float* __restrict__ Wout, const float* __restrict__ bout,
    float* __restrict__ out) {
    __shared__ int sh_lo, sh_hi;
    __shared__ float part[4][64];
    int g = blockIdx.x;
    int t = threadIdx.x;
    if (t == 0) {
        sh_lo = lbound(batch, NN, g);
        sh_hi = lbound(batch, NN, g + 1);
    }
    __syncthreads();
    int lo = sh_lo, hi = sh_hi;
    int c = t & 63, w = t >> 6;
    float s = 0.f;
    for (int n = lo + w; n < hi; n += 4) s += us2f(h[(size_t)n * 64 + c]);
    part[w][c] = s;
    __syncthreads();
    if (t < 64) {
        float tot = part[0][t] + part[1][t] + part[2][t] + part[3][t];
        float cnt = (float)(hi - lo);
        float val = tot / fmaxf(cnt, 1.f) * Wout[t];
        #pragma unroll
        for (int mk = 1; mk < 64; mk <<= 1) val += __shfl_xor(val, mk);
        if (t == 0) out[g] = val + bout[0];
    }
}

extern "C" void kernel_launch(void* const* d_in, const int* in_sizes, int n_in,
                              void* d_out, int out_size, void* d_ws, size_t ws_size,
                              hipStream_t stream) {
    const float* x    = (const float*)d_in[0];
    const int*   ei   = (const int*)d_in[1];
    const int*   batch= (const int*)d_in[2];
    const float* Wq   = (const float*)d_in[4];
    const float* bq   = (const float*)d_in[5];
    const float* Wk   = (const float*)d_in[6];
    const float* bk   = (const float*)d_in[7];
    const float* Wv   = (const float*)d_in[8];
    const float* bv   = (const float*)d_in[9];
    const float* Ws   = (const float*)d_in[10];
    const float* bs   = (const float*)d_in[11];
    const float* lng  = (const float*)d_in[12];
    const float* lnb  = (const float*)d_in[13];
    const float* Wout = (const float*)d_in[14];
    const float* bout = (const float*)d_in[15];
    float* out = (float*)d_out;

    float* q    = (float*)d_ws;
    unsigned short* kvh = (unsigned short*)(q + (size_t)NN * 128);
    float* skip = (float*)(kvh + (size_t)NN * 256);
    unsigned short* xh0 = (unsigned short*)(skip + (size_t)NN * 64);
    unsigned short* xh1 = xh0 + (size_t)NN * 64;
    unsigned short* wt  = xh1 + (size_t)NN * 64;
    int* deg    = (int*)(wt + 3 * WT_LSTRIDE);
    int* rowst  = deg + NN;
    int* cursor = rowst + NN;
    int* bsum   = cursor + NN;
    int* esrc   = bsum + 256;

    hipMemsetAsync(deg, 0, NN * sizeof(int), stream);

    const int NB = (NN + 255) / 256;  // 196
    deg_kernel<<<(EE + 255) / 256, 256, 0, stream>>>(ei, deg);
    scan1<<<NB, 256, 0, stream>>>(deg, rowst, bsum);
    scan2<<<1, 256, 0, stream>>>(bsum, NB);
    scan3<<<NB, 256, 0, stream>>>(rowst, deg, bsum, cursor);
    fill_kernel<<<(EE + 255) / 256, 256, 0, stream>>>(ei, cursor, esrc);

    cast_x_kernel<<<(NN * 16 + 255) / 256, 256, 0, stream>>>(x, xh0);
    pack_w_kernel<<<(3 * WT_LSTRIDE + 255) / 256, 256, 0, stream>>>(Wq, Wk, Wv, Ws, wt);

    const int GEMM_GRID = (NN + 31) / 32;  // 1563
    unsigned short* hin = xh0;
    unsigned short* houts[3] = {xh1, xh0, xh1};
    for (int l = 0; l < 3; ++l) {
        gemm_mfma<<<GEMM_GRID, 256, 0, stream>>>(hin, wt + (size_t)l * WT_LSTRIDE,
            bq + (size_t)l * 128, bk + (size_t)l * 128, bv + (size_t)l * 128,
            bs + (size_t)l * 64, q, kvh, skip);
        int do_ln = (l < 2) ? 1 : 0;
        agg_kernel<<<(NN + 3) / 4, 256, 0, stream>>>(q, kvh, skip, rowst, deg, esrc,
                                                     lng + (size_t)(do_ln ? l : 0) * 64,
                                                     lnb + (size_t)(do_ln ? l : 0) * 64,
                                                     houts[l], do_ln);
        hin = houts[l];
    }
    pool_final_kernel<<<GG, 256, 0, stream>>>(hin, batch, Wout, bout, out);
}

// Round 9
// 404.732 us; speedup vs baseline: 2.9188x; 1.0326x over previous
//
#include <hip/hip_runtime.h>
#include <hip/hip_fp16.h>
#include <math.h>

#define NN 50000
#define EE 800000
#define GG 512

typedef _Float16 f16x8 __attribute__((ext_vector_type(8)));
typedef _Float16 f16x2 __attribute__((ext_vector_type(2)));
typedef float f32x4 __attribute__((ext_vector_type(4)));

#if defined(__has_builtin)
#if __has_builtin(__builtin_amdgcn_fdot2)
#define HAS_FDOT2 1
#endif
#endif

// fold 1/sqrt(64) * log2(e) into q so scores are in log2 domain
#define QSCALE 0.1803368801111244f

__device__ __forceinline__ float wave16_sum(float p) {
    p += __shfl_xor(p, 1);
    p += __shfl_xor(p, 2);
    p += __shfl_xor(p, 4);
    p += __shfl_xor(p, 8);
    return p;
}
__device__ __forceinline__ float2 h2f(unsigned int u) {
    __half2 h = *reinterpret_cast<__half2*>(&u);
    return __half22float2(h);
}
__device__ __forceinline__ unsigned short f2us(float x) {
    return __half_as_ushort(__float2half(x));
}
__device__ __forceinline__ float us2f(unsigned short u) {
    return __half2float(__ushort_as_half(u));
}
__device__ __forceinline__ f16x2 u2h2(unsigned int u) {
    union { unsigned int u; f16x2 h; } x; x.u = u; return x.h;
}
__device__ __forceinline__ float dot2acc(f16x2 a, f16x2 b, float c) {
#ifdef HAS_FDOT2
    return __builtin_amdgcn_fdot2(a, b, c, false);
#else
    return c + (float)a[0] * (float)b[0] + (float)a[1] * (float)b[1];
#endif
}
__device__ __forceinline__ float exp2fast(float x) {
    return __builtin_amdgcn_exp2f(x);
}

// ---------------- CSR build ----------------
__global__ void deg_kernel(const int* __restrict__ ei, int* __restrict__ deg) {
    int e = blockIdx.x * 256 + threadIdx.x;
    if (e < EE) atomicAdd(&deg[ei[EE + e]], 1);
}

__global__ void scan1(const int* __restrict__ deg, int* __restrict__ incl, int* __restrict__ bsum) {
    __shared__ int sh[256];
    int t = threadIdx.x;
    int n = blockIdx.x * 256 + t;
    int vv = (n < NN) ? deg[n] : 0;
    sh[t] = vv; __syncthreads();
    for (int off = 1; off < 256; off <<= 1) {
        int u = (t >= off) ? sh[t - off] : 0;
        __syncthreads();
        sh[t] += u;
        __syncthreads();
    }
    if (n < NN) incl[n] = sh[t];
    if (t == 255) bsum[blockIdx.x] = sh[255];
}

__global__ void scan2(int* __restrict__ bsum, int nblk) {
    __shared__ int sh[256];
    int t = threadIdx.x;
    int vv = (t < nblk) ? bsum[t] : 0;
    sh[t] = vv; __syncthreads();
    for (int off = 1; off < 256; off <<= 1) {
        int u = (t >= off) ? sh[t - off] : 0;
        __syncthreads();
        sh[t] += u;
        __syncthreads();
    }
    bsum[t] = sh[t];
}

__global__ void scan3(int* __restrict__ rowst, const int* __restrict__ deg,
                      const int* __restrict__ bsum, int* __restrict__ cursor) {
    int n = blockIdx.x * 256 + threadIdx.x;
    if (n >= NN) return;
    int off = (blockIdx.x > 0) ? bsum[blockIdx.x - 1] : 0;
    int excl = rowst[n] - deg[n] + off;
    rowst[n] = excl;
    cursor[n] = excl;
}

__global__ void fill_kernel(const int* __restrict__ ei, int* __restrict__ cursor,
                            unsigned short* __restrict__ esrc) {
    int e = blockIdx.x * 256 + threadIdx.x;
    if (e < EE) {
        int s = ei[e], d = ei[EE + e];
        int pos = atomicAdd(&cursor[d], 1);
        esrc[pos] = (unsigned short)s;
    }
}

// ---------------- precompute: fp16 casts ----------------
__global__ void cast_x_kernel(const float* __restrict__ x, unsigned short* __restrict__ xh) {
    int i = blockIdx.x * 256 + threadIdx.x;
    if (i < NN * 16) {
        float4 v = *(const float4*)(x + (size_t)i * 4);
        ushort4 o = make_ushort4(f2us(v.x), f2us(v.y), f2us(v.z), f2us(v.w));
        *(ushort4*)(xh + (size_t)i * 4) = o;
    }
}

// wt layout per layer: [448][64] fp16, wt[c][k] = W[k][c]; c: 0..127 q, 128..255 k, 256..383 v, 384..447 skip
#define WT_LSTRIDE (448 * 64)
__global__ void pack_w_kernel(const float* __restrict__ Wq, const float* __restrict__ Wk,
                              const float* __restrict__ Wv, const float* __restrict__ Ws,
                              unsigned short* __restrict__ wt) {
    int idx = blockIdx.x * 256 + threadIdx.x;
    if (idx >= 3 * WT_LSTRIDE) return;
    int l = idx / WT_LSTRIDE, r = idx % WT_LSTRIDE;
    int c = r / 64, k = r % 64;
    float val;
    if (c < 384) {
        int m = c >> 7, col = c & 127;
        const float* W = (m == 0) ? Wq : ((m == 1) ? Wk : Wv);
        val = W[(size_t)l * 64 * 128 + k * 128 + col];
    } else {
        int col = c - 384;
        val = Ws[(size_t)l * 64 * 64 + k * 64 + col];
    }
    wt[idx] = f2us(val);
}

// ---------------- MFMA GEMM: [NN x 64] fp16 @ [64 x 448] fp16 -> qh(f16,scaled), kvh(f16), skip(f32) ----------------
__global__ __launch_bounds__(256) void gemm_mfma(
    const unsigned short* __restrict__ xh,
    const unsigned short* __restrict__ wt,
    const float* __restrict__ bq, const float* __restrict__ bk,
    const float* __restrict__ bv, const float* __restrict__ bsk,
    unsigned short* __restrict__ qh, unsigned short* __restrict__ kvh,
    float* __restrict__ skip) {
    int t = threadIdx.x;
    int wave = t >> 6, lane = t & 63;
    int li = lane & 15, lh = lane >> 4;
    int row0 = blockIdx.x * 32 + (wave & 1) * 16;
    int ctbase = (wave >> 1) * 14;

    int arow = min(row0 + li, NN - 1);
    const unsigned short* ap = xh + (size_t)arow * 64 + lh * 8;
    f16x8 a0 = *(const f16x8*)(ap);
    f16x8 a1 = *(const f16x8*)(ap + 32);

    int rb = row0 + lh * 4;

    #pragma unroll 2
    for (int tt = 0; tt < 14; ++tt) {
        int c = (ctbase + tt) * 16 + li;
        const unsigned short* bp = wt + (size_t)c * 64 + lh * 8;
        f16x8 b0 = *(const f16x8*)(bp);
        f16x8 b1 = *(const f16x8*)(bp + 32);
        f32x4 d = {0.f, 0.f, 0.f, 0.f};
        d = __builtin_amdgcn_mfma_f32_16x16x32_f16(a0, b0, d, 0, 0, 0);
        d = __builtin_amdgcn_mfma_f32_16x16x32_f16(a1, b1, d, 0, 0, 0);
        if (c < 128) {
            float bias = bq[c];
            #pragma unroll
            for (int e = 0; e < 4; ++e) {
                int r = rb + e;
                if (r < NN) qh[(size_t)r * 128 + c] = f2us((d[e] + bias) * QSCALE);
            }
        } else if (c < 256) {
            int ch = c - 128;
            float bias = bk[ch];
            int off = (ch < 64) ? ((ch >> 2) * 16 + (ch & 3))
                                : (((ch - 64) >> 2) * 16 + 4 + (ch & 3));
            #pragma unroll
            for (int e = 0; e < 4; ++e) {
                int r = rb + e;
                if (r < NN) kvh[(size_t)r * 256 + off] = f2us(d[e] + bias);
            }
        } else if (c < 384) {
            int ch = c - 256;
            float bias = bv[ch];
            int off = 8 + ((ch < 64) ? ((ch >> 2) * 16 + (ch & 3))
                                     : (((ch - 64) >> 2) * 16 + 4 + (ch & 3)));
            #pragma unroll
            for (int e = 0; e < 4; ++e) {
                int r = rb + e;
                if (r < NN) kvh[(size_t)r * 256 + off] = f2us(d[e] + bias);
            }
        } else {
            int ch = c - 384;
            float bias = bsk[ch];
            #pragma unroll
            for (int e = 0; e < 4; ++e) {
                int r = rb + e;
                if (r < NN) skip[(size_t)r * 64 + ch] = d[e] + bias;
            }
        }
    }
}

// ---------------- per-node attention aggregation (fp16 kv, fdot2, log2-domain softmax) ----------------
__global__ __launch_bounds__(256) void agg_kernel(
    const unsigned short* __restrict__ qh, const unsigned short* __restrict__ kvh,
    const float* __restrict__ skip,
    const int* __restrict__ rowst, const int* __restrict__ deg,
    const unsigned short* __restrict__ esrc, const float* __restrict__ gamma,
    const float* __restrict__ beta, unsigned short* __restrict__ hout, int do_ln) {
    int wave = threadIdx.x >> 6;
    int lane = threadIdx.x & 63;
    int node = blockIdx.x * 4 + wave;
    if (node >= NN) return;
    int j = lane & 15;
    int slot = lane >> 4;

    // q halves (pre-scaled by 0.125*log2e): head0 dims j*4..+3, head1 at +64
    uint2 qu0 = *(const uint2*)(qh + (size_t)node * 128 + j * 4);
    uint2 qu1 = *(const uint2*)(qh + (size_t)node * 128 + 64 + j * 4);
    f16x2 q0a = u2h2(qu0.x), q0b = u2h2(qu0.y);
    f16x2 q1a = u2h2(qu1.x), q1b = u2h2(qu1.y);

    float m0 = -1e30f, m1 = -1e30f;
    float l0 = 0.f, l1 = 0.f;
    float acc0[4] = {0.f, 0.f, 0.f, 0.f};
    float acc1[4] = {0.f, 0.f, 0.f, 0.f};

    int st = rowst[node];
    int dg = deg[node];
    for (int base = slot * 2; base < dg; base += 8) {
        int last = dg - 1;
        int s0 = (int)esrc[st + min(base + 0, last)];
        int s1 = (int)esrc[st + min(base + 1, last)];
        const unsigned short* b0 = kvh + (size_t)s0 * 256 + j * 16;
        const unsigned short* b1 = kvh + (size_t)s1 * 256 + j * 16;
        uint4 A0 = *(const uint4*)(b0);       // k0[4],k1[4]
        uint4 B0 = *(const uint4*)(b0 + 8);   // v0[4],v1[4]
        uint4 A1 = *(const uint4*)(b1);
        uint4 B1 = *(const uint4*)(b1 + 8);

        // scores via packed fp16 dot (log2 domain)
        float p00 = dot2acc(q0b, u2h2(A0.y), dot2acc(q0a, u2h2(A0.x), 0.f));
        float p01 = dot2acc(q1b, u2h2(A0.w), dot2acc(q1a, u2h2(A0.z), 0.f));
        float p10 = dot2acc(q0b, u2h2(A1.y), dot2acc(q0a, u2h2(A1.x), 0.f));
        float p11 = dot2acc(q1b, u2h2(A1.w), dot2acc(q1a, u2h2(A1.z), 0.f));
        p00 = wave16_sum(p00);
        p01 = wave16_sum(p01);
        p10 = wave16_sum(p10);
        p11 = wave16_sum(p11);
        if (base + 1 > last) { p10 = -1e30f; p11 = -1e30f; }

        float2 c00 = h2f(B0.x), c01 = h2f(B0.y), c02 = h2f(B0.z), c03 = h2f(B0.w);
        float2 c10 = h2f(B1.x), c11 = h2f(B1.y), c12 = h2f(B1.z), c13 = h2f(B1.w);
        float v00[4] = {c00.x, c00.y, c01.x, c01.y};
        float v01[4] = {c02.x, c02.y, c03.x, c03.y};
        float v10[4] = {c10.x, c10.y, c11.x, c11.y};
        float v11[4] = {c12.x, c12.y, c13.x, c13.y};

        {
            float nm = fmaxf(m0, fmaxf(p00, p10));
            float f = exp2fast(m0 - nm);
            float e0 = exp2fast(p00 - nm);
            float e1 = exp2fast(p10 - nm);
            l0 = l0 * f + e0 + e1;
            #pragma unroll
            for (int r = 0; r < 4; ++r)
                acc0[r] = acc0[r] * f + e0 * v00[r] + e1 * v10[r];
            m0 = nm;
        }
        {
            float nm = fmaxf(m1, fmaxf(p01, p11));
            float f = exp2fast(m1 - nm);
            float e0 = exp2fast(p01 - nm);
            float e1 = exp2fast(p11 - nm);
            l1 = l1 * f + e0 + e1;
            #pragma unroll
            for (int r = 0; r < 4; ++r)
                acc1[r] = acc1[r] * f + e0 * v01[r] + e1 * v11[r];
            m1 = nm;
        }
    }
    // butterfly-merge the 4 slot states (masks 16, 32)
    #pragma unroll
    for (int mask = 16; mask <= 32; mask <<= 1) {
        {
            float mo = __shfl_xor(m0, mask);
            float lo = __shfl_xor(l0, mask);
            float ao[4];
            #pragma unroll
            for (int r = 0; r < 4; ++r) ao[r] = __shfl_xor(acc0[r], mask);
            float nm = fmaxf(m0, mo);
            float fa = exp2fast(m0 - nm);
            float fb = exp2fast(mo - nm);
            l0 = l0 * fa + lo * fb;
            #pragma unroll
            for (int r = 0; r < 4; ++r) acc0[r] = acc0[r] * fa + ao[r] * fb;
            m0 = nm;
        }
        {
            float mo = __shfl_xor(m1, mask);
            float lo = __shfl_xor(l1, mask);
            float ao[4];
            #pragma unroll
            for (int r = 0; r < 4; ++r) ao[r] = __shfl_xor(acc1[r], mask);
            float nm = fmaxf(m1, mo);
            float fa = exp2fast(m1 - nm);
            float fb = exp2fast(mo - nm);
            l1 = l1 * fa + lo * fb;
            #pragma unroll
            for (int r = 0; r < 4; ++r) acc1[r] = acc1[r] * fa + ao[r] * fb;
            m1 = nm;
        }
    }
    float i0 = 1.f / (l0 + 1e-16f);
    float i1 = 1.f / (l1 + 1e-16f);
    float4 sk = *(const float4*)(skip + (size_t)node * 64 + j * 4);
    float ska[4] = {sk.x, sk.y, sk.z, sk.w};
    float val[4];
    #pragma unroll
    for (int r = 0; r < 4; ++r) {
        float o = 0.5f * (acc0[r] * i0 + acc1[r] * i1) + ska[r];
        val[r] = fmaxf(o, 0.f);
    }
    if (do_ln) {
        float s = val[0] + val[1] + val[2] + val[3];
        s = wave16_sum(s);
        float mu = s * (1.f / 64.f);
        float ss = 0.f;
        #pragma unroll
        for (int r = 0; r < 4; ++r) { float d = val[r] - mu; ss += d * d; }
        ss = wave16_sum(ss);
        float rstd = rsqrtf(ss * (1.f / 64.f) + 1e-5f);
        float4 g4 = *(const float4*)(gamma + j * 4);
        float4 b4 = *(const float4*)(beta + j * 4);
        float ga[4] = {g4.x, g4.y, g4.z, g4.w};
        float ba[4] = {b4.x, b4.y, b4.z, b4.w};
        #pragma unroll
        for (int r = 0; r < 4; ++r) val[r] = (val[r] - mu) * rstd * ga[r] + ba[r];
    }
    if (slot == 0) {
        ushort4 o = make_ushort4(f2us(val[0]), f2us(val[1]), f2us(val[2]), f2us(val[3]));
        *(ushort4*)(hout + (size_t)node * 64 + j * 4) = o;
    }
}

// ---------------- fused pool + final projection (batch is sorted) ----------------
__device__ __forceinline__ int lbound(const int* __restrict__ a, int n, int key) {
    int lo = 0, hi = n;
    while (lo < hi) {
        int mid = (lo + hi) >> 1;
        if (a[mid] < key) lo = mid + 1; else hi = mid;
    }
    return lo;
}

__global__ __launch_bounds__(256) void pool_final_kernel(
    const unsigned short* __restrict__ h, const int* __restrict__ batch,
    const float* __restrict__ Wout, const float* __restrict__ bout,
    float* __restrict__ out) {
    __shared__ int sh_lo, sh_hi;
    __shared__ float part[4][64];
    int g = blockIdx.x;
    int t = threadIdx.x;
    if (t == 0) {
        sh_lo = lbound(batch, NN, g);
        sh_hi = lbound(batch, NN, g + 1);
    }
    __syncthreads();
    int lo = sh_lo, hi = sh_hi;
    int c = t & 63, w = t >> 6;
    float s = 0.f;
    for (int n = lo + w; n < hi; n += 4) s += us2f(h[(size_t)n * 64 + c]);
    part[w][c] = s;
    __syncthreads();
    if (t < 64) {
        float tot = part[0][t] + part[1][t] + part[2][t] + part[3][t];
        float cnt = (float)(hi - lo);
        float val = tot / fmaxf(cnt, 1.f) * Wout[t];
        #pragma unroll
        for (int mk = 1; mk < 64; mk <<= 1) val += __shfl_xor(val, mk);
        if (t == 0) out[g] = val + bout[0];
    }
}

extern "C" void kernel_launch(void* const* d_in, const int* in_sizes, int n_in,
                              void* d_out, int out_size, void* d_ws, size_t ws_size,
                              hipStream_t stream) {
    const float* x    = (const float*)d_in[0];
    const int*   ei   = (const int*)d_in[1];
    const int*   batch= (const int*)d_in[2];
    const float* Wq   = (const float*)d_in[4];
    const float* bq   = (const float*)d_in[5];
    const float* Wk   = (const float*)d_in[6];
    const float* bk   = (const float*)d_in[7];
    const float* Wv   = (const float*)d_in[8];
    const float* bv   = (const float*)d_in[9];
    const float* Ws   = (const float*)d_in[10];
    const float* bs   = (const float*)d_in[11];
    const float* lng  = (const float*)d_in[12];
    const float* lnb  = (const float*)d_in[13];
    const float* Wout = (const float*)d_in[14];
    const float* bout = (const float*)d_in[15];
    float* out = (float*)d_out;

    unsigned short* qh  = (unsigned short*)d_ws;
    unsigned short* kvh = qh + (size_t)NN * 128;
    float* skip = (float*)(kvh + (size_t)NN * 256);
    unsigned short* xh0 = (unsigned short*)(skip + (size_t)NN * 64);
    unsigned short* xh1 = xh0 + (size_t)NN * 64;
    unsigned short* wt  = xh1 + (size_t)NN * 64;
    int* deg    = (int*)(wt + 3 * WT_LSTRIDE);
    int* rowst  = deg + NN;
    int* cursor = rowst + NN;
    int* bsum   = cursor + NN;
    unsigned short* esrc = (unsigned short*)(bsum + 256);

    hipMemsetAsync(deg, 0, NN * sizeof(int), stream);

    const int NB = (NN + 255) / 256;  // 196
    deg_kernel<<<(EE + 255) / 256, 256, 0, stream>>>(ei, deg);
    scan1<<<NB, 256, 0, stream>>>(deg, rowst, bsum);
    scan2<<<1, 256, 0, stream>>>(bsum, NB);
    scan3<<<NB, 256, 0, stream>>>(rowst, deg, bsum, cursor);
    fill_kernel<<<(EE + 255) / 256, 256, 0, stream>>>(ei, cursor, esrc);

    cast_x_kernel<<<(NN * 16 + 255) / 256, 256, 0, stream>>>(x, xh0);
    pack_w_kernel<<<(3 * WT_LSTRIDE + 255) / 256, 256, 0, stream>>>(Wq, Wk, Wv, Ws, wt);

    const int GEMM_GRID = (NN + 31) / 32;  // 1563
    unsigned short* hin = xh0;
    unsigned short* houts[3] = {xh1, xh0, xh1};
    for (int l = 0; l < 3; ++l) {
        gemm_mfma<<<GEMM_GRID, 256, 0, stream>>>(hin, wt + (size_t)l * WT_LSTRIDE,
            bq + (size_t)l * 128, bk + (size_t)l * 128, bv + (size_t)l * 128,
            bs + (size_t)l * 64, qh, kvh, skip);
        int do_ln = (l < 2) ? 1 : 0;
        agg_kernel<<<(NN + 3) / 4, 256, 0, stream>>>(qh, kvh, skip, rowst, deg, esrc,
                                                     lng + (size_t)(do_ln ? l : 0) * 64,
                                                     lnb + (size_t)(do_ln ? l : 0) * 64,
                                                     houts[l], do_ln);
        hin = houts[l];
    }
    pool_final_kernel<<<GG, 256, 0, stream>>>(hin, batch, Wout, bout, out);
}